// Round 8
// baseline (5348.523 us; speedup 1.0000x reference)
//
#include <hip/hip_runtime.h>

typedef __bf16 bf16;
typedef __bf16 bf16x8 __attribute__((ext_vector_type(8)));
typedef __bf16 bf16x4 __attribute__((ext_vector_type(4)));
typedef float  f32x4  __attribute__((ext_vector_type(4)));

#define DEV __device__ __forceinline__

// async global->LDS, 16B per lane; lds dest must be wave-uniform base (HW adds lane*16)
DEV void gload_lds16(const bf16* g, bf16* l) {
    __builtin_amdgcn_global_load_lds(
        (__attribute__((address_space(1))) void*)g,
        (__attribute__((address_space(3))) void*)l, 16, 0, 0);
}

// lgkmcnt(0) first: wave's own ds_reads complete before the barrier, so the
// next buffer-overwrite (gload_lds) can never race an in-flight read.
DEV void barrier_raw() {
    asm volatile("s_waitcnt lgkmcnt(0)" ::: "memory");
    __builtin_amdgcn_s_barrier();
    asm volatile("" ::: "memory");
}

enum { M_QKV, M_SCORES, M_PV, M_RESID, M_GELU, M_OUT, M_WM };

// ---------------------------------------------------------------------------
// 128x128 tile GEMM. B staged via 3-buffer 2-ahead gload_lds pipeline;
// A-fragments loaded DIRECTLY global->VGPR (ping-pong, 1 kt ahead) — halves
// LDS traffic per MFMA (LDS was the measured wall, R7). LDS: 3x8KB = 24KB.
// C[m,n] = sum_k A[m,k]*B[n,k]; A:[M,K], B:[N,K] bf16 row-major.
// ---------------------------------------------------------------------------
template<int MODE>
__global__ __launch_bounds__(256)
void gemm_k(const bf16* __restrict__ A, const bf16* __restrict__ B,
            int M, int N, int K,
            long long batchA, long long batchB, long long batchC,
            const float* __restrict__ bias,
            bf16* __restrict__ Cb, float* __restrict__ Cf,
            bf16* __restrict__ qp, bf16* __restrict__ kp, bf16* __restrict__ vp)
{
    const int bm = blockIdx.x, bn = blockIdx.y, bz = blockIdx.z;
    const int kTiles = K >> 5;

    const int tid = threadIdx.x, wid = tid >> 6, lane = tid & 63;
    const bf16* Ab = A + (long long)bz * batchA + (long long)bm * 128 * K;
    const bf16* Bb = B + (long long)bz * batchB + (long long)bn * 128 * K;

    extern __shared__ __align__(16) bf16 sB[];   // [3][4096] = 24KB

    const int srow = wid * 16 + (lane >> 2);
    const int scol = (lane & 3) * 8;
    const long long boff = (long long)srow * K + scol;

    auto stageB = [&](int buf, int kt) {
        const bf16* gb = Bb + (long long)kt * 32 + boff;
        bf16* b = sB + buf * 4096;
        gload_lds16(gb,            b + (wid * 16) * 32);
        gload_lds16(gb + 64LL * K, b + (64 + wid * 16) * 32);
    };

    const int wr = wid >> 1, wc = wid & 1;
    const int arow = wr * 64 + (lane & 15);
    const int brow = wc * 64 + (lane & 15);
    const int koff = (lane >> 4) * 8;

    auto loadA = [&](bf16x8 (&af)[4], int kt) {
#pragma unroll
        for (int m = 0; m < 4; ++m)
            af[m] = *(const bf16x8*)(Ab + (long long)(arow + m * 16) * K + kt * 32 + koff);
    };

    f32x4 acc[4][4];
#pragma unroll
    for (int m = 0; m < 4; ++m)
#pragma unroll
        for (int n = 0; n < 4; ++n) acc[m][n] = (f32x4){0.f, 0.f, 0.f, 0.f};

    bf16x8 afA[4], afB[4];
    stageB(0, 0);
    if (kTiles > 1) stageB(1, 1);
    loadA(afA, 0);

    // one sub-iteration; afc = current A regs, afn = next (filled here)
    auto body = [&](bf16x8 (&afc)[4], bf16x8 (&afn)[4], int kt) {
        if (kt + 2 < kTiles) asm volatile("s_waitcnt vmcnt(2)" ::: "memory");
        else                 asm volatile("s_waitcnt vmcnt(0)" ::: "memory");
        barrier_raw();
        if (kt + 1 < kTiles) loadA(afn, kt + 1);
        if (kt + 2 < kTiles) {
            int b3 = (kt + 2) % 3;
            stageB(b3, kt + 2);
        }
        const bf16* b = sB + (kt % 3) * 4096;
        bf16x8 bfr[4];
#pragma unroll
        for (int n = 0; n < 4; ++n)
            bfr[n] = *(const bf16x8*)&b[(brow + n * 16) * 32 + koff];
#pragma unroll
        for (int m = 0; m < 4; ++m)
#pragma unroll
            for (int n = 0; n < 4; ++n)
                acc[m][n] = __builtin_amdgcn_mfma_f32_16x16x32_bf16(afc[m], bfr[n], acc[m][n], 0, 0, 0);
    };

    for (int kt = 0; kt < kTiles; kt += 2) {     // kTiles always even here
        body(afA, afB, kt);
        body(afB, afA, kt + 1);
    }

    // C/D layout: col = lane&15, row = (lane>>4)*4 + r   [learn_hip m89]
    const int cr0 = bm * 128 + wr * 64 + (lane >> 4) * 4;
    const int cc0 = bn * 128 + wc * 64 + (lane & 15);
#pragma unroll
    for (int m = 0; m < 4; ++m) {
#pragma unroll
        for (int n = 0; n < 4; ++n) {
            const int col = cc0 + n * 16;
#pragma unroll
            for (int r = 0; r < 4; ++r) {
                const int row = cr0 + m * 16 + r;
                float v = acc[m][n][r];
                if (MODE == M_QKV) {
                    v += bias[col];
                    int hd = col / 192, rr = col % 192;
                    int b2 = row >> 10, s = row & 1023;
                    if (rr < 64)
                        qp[(long long)row * 768 + hd * 64 + rr] = (bf16)(v * 0.03608439182435161f);
                    else if (rr < 128)
                        kp[(long long)row * 768 + hd * 64 + (rr - 64)] = (bf16)v;
                    else
                        vp[((long long)b2 * 768 + hd * 64 + (rr - 128)) * 1024 + s] = (bf16)v;
                } else if (MODE == M_GELU) {
                    float xg = v + bias[col];
                    Cb[(long long)row * N + col] = (bf16)(xg / (1.f + __expf(-1.702f * xg)));
                } else if (MODE == M_RESID) {
                    long long idx = (long long)row * N + col;
                    Cf[idx] += v + bias[col];
                } else if (MODE == M_WM) {
                    Cb[(long long)bz * batchC + (long long)row * N + col] = (bf16)v;
                } else { // M_OUT (fp32 + bias)
                    Cf[(long long)row * N + col] = v + bias[col];
                }
            }
        }
    }
}

// ---------------------------------------------------------------------------
// 64x128 tile GEMM, same A-in-registers + B-only LDS pipeline (24KB).
// For scores/PV (causal granularity) and balanced 768/1024-block grids
// (mlp2, o-merged, final out).
// ---------------------------------------------------------------------------
template<int MODE>
__global__ __launch_bounds__(256)
void gemm64_k(const bf16* __restrict__ A, const bf16* __restrict__ B,
              int M, int N, int K,
              long long batchA, long long batchB, long long batchC,
              const float* __restrict__ bias,
              bf16* __restrict__ Cb, float* __restrict__ Cf)
{
    const int bm = blockIdx.x, bn = blockIdx.y, bz = blockIdx.z;
    if (MODE == M_SCORES && 2 * bn > bm) return;     // fully-masked tile
    int kTiles = K >> 5;
    if (MODE == M_PV) {                              // P[:,k]==0 for k>row
        int lim = 2 * bm + 2;                        // even
        if (lim < kTiles) kTiles = lim;
    }

    const int tid = threadIdx.x, wid = tid >> 6, lane = tid & 63;
    const bf16* Ab = A + (long long)bz * batchA + (long long)bm * 64 * K;
    const bf16* Bb = B + (long long)bz * batchB + (long long)bn * 128 * K;

    extern __shared__ __align__(16) bf16 sB[];   // [3][4096] = 24KB

    const int srow = wid * 16 + (lane >> 2);
    const int scol = (lane & 3) * 8;
    const long long boff = (long long)srow * K + scol;

    auto stageB = [&](int buf, int kt) {
        const bf16* gb = Bb + (long long)kt * 32 + boff;
        bf16* b = sB + buf * 4096;
        gload_lds16(gb,            b + (wid * 16) * 32);
        gload_lds16(gb + 64LL * K, b + (64 + wid * 16) * 32);
    };

    const int wr = wid >> 1, wc = wid & 1;
    const int arow = wr * 32 + (lane & 15);
    const int brow = wc * 64 + (lane & 15);
    const int koff = (lane >> 4) * 8;

    auto loadA = [&](bf16x8 (&af)[2], int kt) {
#pragma unroll
        for (int m = 0; m < 2; ++m)
            af[m] = *(const bf16x8*)(Ab + (long long)(arow + m * 16) * K + kt * 32 + koff);
    };

    f32x4 acc[2][4];
#pragma unroll
    for (int m = 0; m < 2; ++m)
#pragma unroll
        for (int n = 0; n < 4; ++n) acc[m][n] = (f32x4){0.f, 0.f, 0.f, 0.f};

    bf16x8 afA[2], afB[2];
    stageB(0, 0);
    if (kTiles > 1) stageB(1, 1);
    loadA(afA, 0);

    auto body = [&](bf16x8 (&afc)[2], bf16x8 (&afn)[2], int kt) {
        if (kt + 2 < kTiles) asm volatile("s_waitcnt vmcnt(2)" ::: "memory");
        else                 asm volatile("s_waitcnt vmcnt(0)" ::: "memory");
        barrier_raw();
        if (kt + 1 < kTiles) loadA(afn, kt + 1);
        if (kt + 2 < kTiles) {
            int b3 = (kt + 2) % 3;
            stageB(b3, kt + 2);
        }
        const bf16* b = sB + (kt % 3) * 4096;
        bf16x8 bfr[4];
#pragma unroll
        for (int n = 0; n < 4; ++n)
            bfr[n] = *(const bf16x8*)&b[(brow + n * 16) * 32 + koff];
#pragma unroll
        for (int m = 0; m < 2; ++m)
#pragma unroll
            for (int n = 0; n < 4; ++n)
                acc[m][n] = __builtin_amdgcn_mfma_f32_16x16x32_bf16(afc[m], bfr[n], acc[m][n], 0, 0, 0);
    };

    for (int kt = 0; kt < kTiles; kt += 2) {     // kTiles even in all uses
        body(afA, afB, kt);
        body(afB, afA, kt + 1);
    }

    const int cr0 = bm * 64 + wr * 32 + (lane >> 4) * 4;
    const int cc0 = bn * 128 + wc * 64 + (lane & 15);
#pragma unroll
    for (int m = 0; m < 2; ++m) {
#pragma unroll
        for (int n = 0; n < 4; ++n) {
            const int col = cc0 + n * 16;
#pragma unroll
            for (int r = 0; r < 4; ++r) {
                const int row = cr0 + m * 16 + r;
                float v = acc[m][n][r];
                if (MODE == M_SCORES || MODE == M_PV) {
                    Cb[(long long)bz * batchC + (long long)row * N + col] = (bf16)v;
                } else if (MODE == M_RESID) {
                    long long idx = (long long)row * N + col;
                    Cf[idx] += v + bias[col];
                } else { // M_OUT (fp32 + bias)
                    Cf[(long long)row * N + col] = v + bias[col];
                }
            }
        }
    }
}

// ---------------------------------------------------------------------------
__global__ __launch_bounds__(256)
void cvt_bf16_k(const float* __restrict__ in, bf16* __restrict__ out, int n4)
{
    int i = blockIdx.x * 256 + threadIdx.x;
    if (i >= n4) return;
    float4 f = ((const float4*)in)[i];
    bf16x4 o = { (bf16)f.x, (bf16)f.y, (bf16)f.z, (bf16)f.w };
    ((bf16x4*)out)[i] = o;
}

// out[l][c][r] = (bf16) in[l][r][c]   (n x n per layer, n mult of 32)
__global__ __launch_bounds__(256)
void transpose_cvt_k(const float* __restrict__ in, bf16* __restrict__ out, int n)
{
    __shared__ float t[32][33];
    const int l = blockIdx.z;
    const int r0 = blockIdx.y * 32, c0 = blockIdx.x * 32;
    const float* src = in + (long long)l * n * n;
    bf16* dst = out + (long long)l * n * n;
    const int tx = threadIdx.x & 31, ty = threadIdx.x >> 5;   // 32x8
#pragma unroll
    for (int i = 0; i < 32; i += 8)
        t[ty + i][tx] = src[(long long)(r0 + ty + i) * n + c0 + tx];
    __syncthreads();
#pragma unroll
    for (int i = 0; i < 32; i += 8)
        dst[(long long)(c0 + ty + i) * n + r0 + tx] = (bf16)t[tx][ty + i];
}

// merged bias: bm[l][a] = sum_j o2w[l][a][j]*o1b[l][j] + o2b[l][a]; one wave per (l,a)
__global__ __launch_bounds__(256)
void bias_merge_k(const float* __restrict__ o2w, const float* __restrict__ o1b,
                  const float* __restrict__ o2b, float* __restrict__ bm, int total)
{
    const int wid = threadIdx.x >> 6, lane = threadIdx.x & 63;
    const int idx = blockIdx.x * 4 + wid;
    if (idx >= total) return;
    const int l = idx / 768, a = idx - l * 768;
    const float* wrow = o2w + ((long long)l * 768 + a) * 768;
    const float* brow = o1b + (long long)l * 768;
    float s = 0.f;
#pragma unroll
    for (int j = 0; j < 12; ++j) {
        int c = j * 64 + lane;
        s += wrow[c] * brow[c];
    }
#pragma unroll
    for (int o = 32; o; o >>= 1) s += __shfl_down(s, o);
    if (lane == 0) bm[idx] = s + o2b[(long long)l * 768 + a];
}

__global__ __launch_bounds__(256)
void cond_proj_k(const float* __restrict__ label, const float* __restrict__ sw,
                 const float* __restrict__ bw, float* __restrict__ scale,
                 float* __restrict__ bias, int total)
{
    int idx = blockIdx.x * 256 + threadIdx.x;
    if (idx >= total) return;
    int l = idx / 6144;
    int rem = idx - l * 6144;
    int b = rem / 768, d = rem - (rem / 768) * 768;
    const float* lab = label + b * 17;
    const float* swp = sw + ((long long)l * 768 + d) * 17;
    const float* bwp = bw + ((long long)l * 768 + d) * 17;
    float s = 0.f, bb = 0.f;
#pragma unroll
    for (int c = 0; c < 17; ++c) { float lv = lab[c]; s += lv * swp[c]; bb += lv * bwp[c]; }
    scale[idx] = s;
    bias[idx]  = bb;
}

// h[b,s,:] = (s==0 ? sos : xe[b,s-1,:]) + pos_bias(s)
__global__ __launch_bounds__(256)
void shift_pos_k(const float* __restrict__ xe, const float* __restrict__ sos,
                 const float* __restrict__ p0, const float* __restrict__ p1,
                 const float* __restrict__ p2, float* __restrict__ h)
{
    const int s = blockIdx.x, b = blockIdx.y;
    const int i0 = s >> 8, i1 = (s >> 4) & 15, i2 = s & 15;
    const float* xr = xe + ((long long)b * 1024 + (s - 1)) * 768;
#pragma unroll
    for (int j = 0; j < 3; ++j) {
        const int d = j * 256 + threadIdx.x;
        float v = (s == 0) ? sos[d] : xr[d];
        float pbv = (d < 256) ? p0[i0 * 256 + d]
                  : (d < 512) ? p1[i1 * 256 + (d - 256)]
                              : p2[i2 * 256 + (d - 512)];
        h[((long long)b * 1024 + s) * 768 + d] = v + pbv;
    }
}

__global__ __launch_bounds__(256)
void cond_ln_k(const float* __restrict__ h, const float* __restrict__ scale,
               const float* __restrict__ bias, bf16* __restrict__ out)
{
    const long long row = (long long)blockIdx.y * 1024 + blockIdx.x;
    const int b = blockIdx.y;
    const float* hr = h + row * 768;
    float v[3], sum = 0.f, sq = 0.f;
#pragma unroll
    for (int j = 0; j < 3; ++j) {
        v[j] = hr[j * 256 + threadIdx.x];
        sum += v[j]; sq += v[j] * v[j];
    }
    __shared__ float sm[8];
#pragma unroll
    for (int o = 32; o; o >>= 1) { sum += __shfl_down(sum, o); sq += __shfl_down(sq, o); }
    const int wid = threadIdx.x >> 6;
    if ((threadIdx.x & 63) == 0) { sm[wid] = sum; sm[4 + wid] = sq; }
    __syncthreads();
    sum = sm[0] + sm[1] + sm[2] + sm[3];
    sq  = sm[4] + sm[5] + sm[6] + sm[7];
    const float mean = sum * (1.f / 768.f);
    const float var  = sq * (1.f / 768.f) - mean * mean;
    const float rs   = rsqrtf(var + 1e-6f);
    const float* sc = scale + (long long)b * 768;
    const float* bi = bias  + (long long)b * 768;
    bf16* orow = out + row * 768;
#pragma unroll
    for (int j = 0; j < 3; ++j) {
        const int d = j * 256 + threadIdx.x;
        orow[d] = (bf16)((v[j] - mean) * rs * (1.f + sc[d]) + bi[d]);
    }
}

// causal softmax over row i. Touches only cols < ceil64(i+1).
__global__ __launch_bounds__(256)
void softmax_k(bf16* __restrict__ P)
{
    const int i = blockIdx.x, b = blockIdx.y;
    bf16* row = P + ((long long)b * 1024 + i) * 1024;
    const int len = i + 1;
    const int lim = (i | 63) + 1;          // 64-col boundary PV can read up to
    float v[4], mx = -1e30f;
#pragma unroll
    for (int j = 0; j < 4; ++j) {
        int c = j * 256 + threadIdx.x;
        v[j] = (c < len) ? (float)row[c] : -1e30f;
        mx = fmaxf(mx, v[j]);
    }
    __shared__ float sm[8];
#pragma unroll
    for (int o = 32; o; o >>= 1) mx = fmaxf(mx, __shfl_down(mx, o));
    const int wid = threadIdx.x >> 6;
    if ((threadIdx.x & 63) == 0) sm[wid] = mx;
    __syncthreads();
    mx = fmaxf(fmaxf(sm[0], sm[1]), fmaxf(sm[2], sm[3]));
    float s = 0.f;
#pragma unroll
    for (int j = 0; j < 4; ++j) {
        v[j] = __expf(v[j] - mx);
        s += ((j * 256 + threadIdx.x) < len) ? v[j] : 0.f;
    }
#pragma unroll
    for (int o = 32; o; o >>= 1) s += __shfl_down(s, o);
    if ((threadIdx.x & 63) == 0) sm[4 + wid] = s;
    __syncthreads();
    s = sm[4] + sm[5] + sm[6] + sm[7];
    const float inv = 1.f / s;
#pragma unroll
    for (int j = 0; j < 4; ++j) {
        int c = j * 256 + threadIdx.x;
        if (c < lim) row[c] = (c < len) ? (bf16)(v[j] * inv) : (bf16)0.f;
    }
}

__global__ __launch_bounds__(256)
void fill_k(float* o, int n, float v)
{
    int i = blockIdx.x * 256 + threadIdx.x;
    if (i < n) o[i] = v;
}

// ---------------------------------------------------------------------------
extern "C" void kernel_launch(void* const* d_in, const int* in_sizes, int n_in,
                              void* d_out, int out_size, void* d_ws, size_t ws_size,
                              hipStream_t stream)
{
    (void)in_sizes; (void)n_in;
    const float* x     = (const float*)d_in[0];
    const float* label = (const float*)d_in[2];
    const float* dw    = (const float*)d_in[3];
    const float* db    = (const float*)d_in[4];
    const float* sos   = (const float*)d_in[5];
    const float* p0    = (const float*)d_in[6];
    const float* p1    = (const float*)d_in[7];
    const float* p2    = (const float*)d_in[8];
    const float* ln1sw = (const float*)d_in[9];
    const float* ln1bw = (const float*)d_in[10];
    const float* qkvw  = (const float*)d_in[11];
    const float* qkvb  = (const float*)d_in[12];
    const float* ao1w  = (const float*)d_in[13];
    const float* ao1b  = (const float*)d_in[14];
    const float* ao2w  = (const float*)d_in[15];
    const float* ao2b  = (const float*)d_in[16];
    const float* ln2sw = (const float*)d_in[17];
    const float* ln2bw = (const float*)d_in[18];
    const float* m1w   = (const float*)d_in[19];
    const float* m1b   = (const float*)d_in[20];
    const float* m2w   = (const float*)d_in[21];
    const float* m2b   = (const float*)d_in[22];
    const float* lnfsw = (const float*)d_in[23];
    const float* lnfbw = (const float*)d_in[24];
    const float* outw  = (const float*)d_in[25];
    const float* outb  = (const float*)d_in[26];
    float* out = (float*)d_out;

    char* p = (char*)d_ws;
    auto alloc = [&](size_t bytes) { void* r = (void*)p; p += (bytes + 255) & ~(size_t)255; return r; };
    float* h    = (float*)alloc(8192LL * 768 * 4);
    bf16*  hn   = (bf16*) alloc(8192LL * 768 * 2);
    bf16*  q    = (bf16*) alloc(8192LL * 768 * 2);
    bf16*  kbuf = (bf16*) alloc(8192LL * 768 * 2);
    bf16*  vT   = (bf16*) alloc(8192LL * 768 * 2);   // [B,768,1024]
    bf16*  P    = (bf16*) alloc(8LL * 1024 * 1024 * 2);
    bf16*  attn = (bf16*) alloc(8192LL * 768 * 2);
    bf16*  mb   = (bf16*) alloc(8192LL * 3072 * 2);
    bf16*  wout = (bf16*) alloc(1024LL * 768 * 2);
    bf16*  wmA  = (bf16*) alloc(12LL * 768 * 768 * 2);   // merged o2@o1, bf16
    float* bmA  = (float*)alloc(12LL * 768 * 4);         // merged o-bias
    float* s1   = (float*)alloc(12LL * 8 * 768 * 4);
    float* b1   = (float*)alloc(12LL * 8 * 768 * 4);
    float* s2   = (float*)alloc(12LL * 8 * 768 * 4);
    float* b2   = (float*)alloc(12LL * 8 * 768 * 4);
    float* sf   = (float*)alloc(8LL * 768 * 4);
    float* bfb  = (float*)alloc(8LL * 768 * 4);

    size_t base_needed = (size_t)(p - (char*)d_ws);
    if (base_needed + 16LL * 1024 * 1024 > ws_size) {
        fill_k<<<(out_size + 255) / 256, 256, 0, stream>>>(out, out_size, 1e9f);
        return;
    }

    // weight conversion: all-layers-at-once if ws allows, else per-layer
    const long long SZ_QKV = 2304LL * 768, SZ_O = 768LL * 768, SZ_M = 3072LL * 768;
    size_t all_bytes = (size_t)(12 * (SZ_QKV + 2 * SZ_M)) * 2;
    bool allw = ((size_t)(p - (char*)d_ws) + all_bytes + 4096 <= ws_size);

    bf16 *wqkvA, *wm1A, *wm2A;
    if (allw) {
        wqkvA = (bf16*)alloc(12 * SZ_QKV * 2);
        wm1A  = (bf16*)alloc(12 * SZ_M * 2);
        wm2A  = (bf16*)alloc(12 * SZ_M * 2);
    } else {
        wqkvA = (bf16*)alloc(SZ_QKV * 2);
        wm1A  = (bf16*)alloc(SZ_M * 2);
        wm2A  = (bf16*)alloc(SZ_M * 2);
    }

    // one-time scratch aliased onto regions unused until the layer loop:
    bf16*  xbf   = (bf16*)P;
    bf16*  dwbf  = (bf16*)P + 524288;
    bf16*  wo2bf = (bf16*)P + 1048576;
    float* xe    = (float*)mb;
    bf16*  o1t   = mb + 12582912;

    // --- one-time precompute ---
    cvt_bf16_k<<<1024 * 768 / 4 / 256, 256, 0, stream>>>(outw, wout, 1024 * 768 / 4);
    cond_proj_k<<<(12 * 8 * 768 + 255) / 256, 256, 0, stream>>>(label, ln1sw, ln1bw, s1, b1, 12 * 8 * 768);
    cond_proj_k<<<(12 * 8 * 768 + 255) / 256, 256, 0, stream>>>(label, ln2sw, ln2bw, s2, b2, 12 * 8 * 768);
    cond_proj_k<<<(8 * 768 + 255) / 256, 256, 0, stream>>>(label, lnfsw, lnfbw, sf, bfb, 8 * 768);

    if (allw) {
        cvt_bf16_k<<<(int)(12 * SZ_QKV / 4 / 256), 256, 0, stream>>>(qkvw, wqkvA, (int)(12 * SZ_QKV / 4));
        cvt_bf16_k<<<(int)(12 * SZ_M / 4 / 256),   256, 0, stream>>>(m1w,  wm1A,  (int)(12 * SZ_M / 4));
        cvt_bf16_k<<<(int)(12 * SZ_M / 4 / 256),   256, 0, stream>>>(m2w,  wm2A,  (int)(12 * SZ_M / 4));
    }

    // merged out-proj: Wm[l] = o2[l] @ o1[l]  (bf16), bm[l] = o2[l]@o1b[l] + o2b[l]
    cvt_bf16_k<<<(int)(12 * SZ_O / 4 / 256), 256, 0, stream>>>(ao2w, wo2bf, (int)(12 * SZ_O / 4));
    transpose_cvt_k<<<dim3(24, 24, 12), 256, 0, stream>>>(ao1w, o1t, 768);
    gemm_k<M_WM><<<dim3(6, 6, 12), 256, 24576, stream>>>(
        wo2bf, o1t, 768, 768, 768, SZ_O, SZ_O, SZ_O,
        nullptr, wmA, nullptr, nullptr, nullptr, nullptr);
    bias_merge_k<<<(12 * 768 + 3) / 4, 256, 0, stream>>>(ao2w, ao1b, ao2b, bmA, 12 * 768);

    // embed: x->bf16, xe = x @ dw^T + db (fp32), then shift+pos
    cvt_bf16_k<<<8192 * 64 / 4 / 256, 256, 0, stream>>>(x, xbf, 8192 * 64 / 4);
    cvt_bf16_k<<<768 * 64 / 4 / 256, 256, 0, stream>>>(dw, dwbf, 768 * 64 / 4);
    gemm_k<M_OUT><<<dim3(64, 6, 1), 256, 24576, stream>>>(
        xbf, dwbf, 8192, 768, 64, 0, 0, 0, db, nullptr, xe, nullptr, nullptr, nullptr);
    shift_pos_k<<<dim3(1024, 8), 256, 0, stream>>>(xe, sos, p0, p1, p2, h);

    for (int l = 0; l < 12; ++l) {
        bf16 *wqkv, *wm1, *wm2;
        if (allw) {
            wqkv = wqkvA + (long long)l * SZ_QKV;
            wm1  = wm1A  + (long long)l * SZ_M;
            wm2  = wm2A  + (long long)l * SZ_M;
        } else {
            wqkv = wqkvA; wm1 = wm1A; wm2 = wm2A;
            cvt_bf16_k<<<(int)(SZ_QKV / 4 / 256), 256, 0, stream>>>(qkvw + (long long)l * SZ_QKV, wqkv, (int)(SZ_QKV / 4));
            cvt_bf16_k<<<(int)(SZ_M / 4 / 256),   256, 0, stream>>>(m1w  + (long long)l * SZ_M,   wm1,  (int)(SZ_M / 4));
            cvt_bf16_k<<<(int)(SZ_M / 4 / 256),   256, 0, stream>>>(m2w  + (long long)l * SZ_M,   wm2,  (int)(SZ_M / 4));
        }

        cond_ln_k<<<dim3(1024, 8), 256, 0, stream>>>(h, s1 + (long long)l * 6144, b1 + (long long)l * 6144, hn);

        gemm_k<M_QKV><<<dim3(64, 18, 1), 256, 24576, stream>>>(
            hn, wqkv, 8192, 2304, 768, 0, 0, 0,
            qkvb + (long long)l * 2304, nullptr, nullptr, q, kbuf, vT);

        gemm64_k<M_SCORES><<<dim3(16, 8, 8), 256, 24576, stream>>>(
            q, kbuf, 1024, 1024, 768, 1024LL * 768, 1024LL * 768, 1024LL * 1024,
            nullptr, P, nullptr);

        softmax_k<<<dim3(1024, 8), 256, 0, stream>>>(P);

        gemm64_k<M_PV><<<dim3(16, 6, 8), 256, 24576, stream>>>(
            P, vT, 1024, 768, 1024, 1024LL * 1024, 768LL * 1024, 1024LL * 768,
            nullptr, attn, nullptr);

        // merged out-proj (o2@o1 fused), residual add into h  (768-block grid)
        gemm64_k<M_RESID><<<dim3(128, 6, 1), 256, 24576, stream>>>(
            attn, wmA + (long long)l * SZ_O, 8192, 768, 768, 0, 0, 0,
            bmA + (long long)l * 768, nullptr, h);

        cond_ln_k<<<dim3(1024, 8), 256, 0, stream>>>(h, s2 + (long long)l * 6144, b2 + (long long)l * 6144, hn);

        gemm_k<M_GELU><<<dim3(64, 24, 1), 256, 24576, stream>>>(
            hn, wm1, 8192, 3072, 768, 0, 0, 0,
            m1b + (long long)l * 3072, mb, nullptr, nullptr, nullptr, nullptr);

        // mlp2, residual add into h  (768-block grid, exactly 3 blocks/CU)
        gemm64_k<M_RESID><<<dim3(128, 6, 1), 256, 24576, stream>>>(
            mb, wm2, 8192, 768, 3072, 0, 0, 0,
            m2b + (long long)l * 768, nullptr, h);
    }

    cond_ln_k<<<dim3(1024, 8), 256, 0, stream>>>(h, sf, bfb, hn);
    gemm64_k<M_OUT><<<dim3(128, 8, 1), 256, 24576, stream>>>(
        hn, wout, 8192, 1024, 768, 0, 0, 0,
        outb, nullptr, out);
}

// Round 9
// 4623.965 us; speedup vs baseline: 1.1567x; 1.1567x over previous
//
#include <hip/hip_runtime.h>

typedef __bf16 bf16;
typedef __bf16 bf16x8 __attribute__((ext_vector_type(8)));
typedef __bf16 bf16x4 __attribute__((ext_vector_type(4)));
typedef float  f32x4  __attribute__((ext_vector_type(4)));

#define DEV __device__ __forceinline__

// async global->LDS, 16B per lane; lds dest must be wave-uniform base (HW adds lane*16)
DEV void gload_lds16(const bf16* g, bf16* l) {
    __builtin_amdgcn_global_load_lds(
        (__attribute__((address_space(1))) void*)g,
        (__attribute__((address_space(3))) void*)l, 16, 0, 0);
}

// lgkmcnt(0) first: wave's own ds_reads complete before the barrier, so the
// next buffer-overwrite (gload_lds) can never race an in-flight read.
DEV void barrier_raw() {
    asm volatile("s_waitcnt lgkmcnt(0)" ::: "memory");
    __builtin_amdgcn_s_barrier();
    asm volatile("" ::: "memory");
}

enum { M_QKV, M_SCORES, M_PV, M_RESID, M_GELU, M_OUT, M_WM };

// ---------------------------------------------------------------------------
// 128x128 tile GEMM (R7 form): A+B in LDS, 3-buffer 2-ahead counted-vmcnt.
// C[m,n] = sum_k A[m,k]*B[n,k]; A:[M,K], B:[N,K] bf16 row-major. LDS 48KB.
// ---------------------------------------------------------------------------
template<int MODE>
__global__ __launch_bounds__(256)
void gemm_k(const bf16* __restrict__ A, const bf16* __restrict__ B,
            int M, int N, int K,
            long long batchA, long long batchB, long long batchC,
            const float* __restrict__ bias,
            bf16* __restrict__ Cb, float* __restrict__ Cf,
            bf16* __restrict__ qp, bf16* __restrict__ kp, bf16* __restrict__ vp)
{
    const int bm = blockIdx.x, bn = blockIdx.y, bz = blockIdx.z;
    const int kTiles = K >> 5;

    const int tid = threadIdx.x, wid = tid >> 6, lane = tid & 63;
    const bf16* Ab = A + (long long)bz * batchA + (long long)bm * 128 * K;
    const bf16* Bb = B + (long long)bz * batchB + (long long)bn * 128 * K;

    extern __shared__ __align__(16) bf16 smem[];   // 24576 elems = 48KB
    bf16* sA = smem;            // [3][4096]
    bf16* sB = smem + 12288;    // [3][4096]

    const int srow = wid * 16 + (lane >> 2);
    const int scol = (lane & 3) * 8;
    const long long aoff = (long long)srow * K + scol;

    auto stage = [&](int buf, int kt) {
        const bf16* ga = Ab + (long long)kt * 32;
        const bf16* gb = Bb + (long long)kt * 32;
        bf16* a = sA + buf * 4096;
        bf16* b = sB + buf * 4096;
        gload_lds16(ga + aoff,            a + (wid * 16) * 32);
        gload_lds16(ga + aoff + 64LL * K, a + (64 + wid * 16) * 32);
        gload_lds16(gb + aoff,            b + (wid * 16) * 32);
        gload_lds16(gb + aoff + 64LL * K, b + (64 + wid * 16) * 32);
    };

    f32x4 acc[4][4];
#pragma unroll
    for (int m = 0; m < 4; ++m)
#pragma unroll
        for (int n = 0; n < 4; ++n) acc[m][n] = (f32x4){0.f, 0.f, 0.f, 0.f};

    const int npre = kTiles < 2 ? kTiles : 2;
    for (int t = 0; t < npre; ++t) stage(t, t);

    const int wr = wid >> 1, wc = wid & 1;
    const int arow = wr * 64 + (lane & 15);
    const int brow = wc * 64 + (lane & 15);
    const int koff = (lane >> 4) * 8;

    int cur = 0;
    for (int kt = 0; kt < kTiles; ++kt) {
        if (kt + 1 < kTiles) asm volatile("s_waitcnt vmcnt(4)" ::: "memory");
        else                 asm volatile("s_waitcnt vmcnt(0)" ::: "memory");
        barrier_raw();   // all waves: stage(kt) visible; iter kt-1 reads done
        if (kt + 2 < kTiles) {
            int ib = cur - 1; if (ib < 0) ib = 2;   // (cur+2)%3
            stage(ib, kt + 2);
        }

        const bf16* a = sA + cur * 4096;
        const bf16* b = sB + cur * 4096;
        bf16x8 af[4], bfr[4];
#pragma unroll
        for (int m = 0; m < 4; ++m)
            af[m] = *(const bf16x8*)&a[(arow + m * 16) * 32 + koff];
#pragma unroll
        for (int n = 0; n < 4; ++n)
            bfr[n] = *(const bf16x8*)&b[(brow + n * 16) * 32 + koff];
#pragma unroll
        for (int m = 0; m < 4; ++m)
#pragma unroll
            for (int n = 0; n < 4; ++n)
                acc[m][n] = __builtin_amdgcn_mfma_f32_16x16x32_bf16(af[m], bfr[n], acc[m][n], 0, 0, 0);

        cur = (cur == 2) ? 0 : cur + 1;
    }

    // C/D layout: col = lane&15, row = (lane>>4)*4 + r   [learn_hip m89]
    const int cr0 = bm * 128 + wr * 64 + (lane >> 4) * 4;
    const int cc0 = bn * 128 + wc * 64 + (lane & 15);
#pragma unroll
    for (int m = 0; m < 4; ++m) {
#pragma unroll
        for (int n = 0; n < 4; ++n) {
            const int col = cc0 + n * 16;
#pragma unroll
            for (int r = 0; r < 4; ++r) {
                const int row = cr0 + m * 16 + r;
                float v = acc[m][n][r];
                if (MODE == M_QKV) {
                    v += bias[col];
                    int hd = col / 192, rr = col % 192;
                    int b2 = row >> 10, s = row & 1023;
                    if (rr < 64)
                        qp[(long long)row * 768 + hd * 64 + rr] = (bf16)(v * 0.03608439182435161f);
                    else if (rr < 128)
                        kp[(long long)row * 768 + hd * 64 + (rr - 64)] = (bf16)v;
                    else
                        vp[((long long)b2 * 768 + hd * 64 + (rr - 128)) * 1024 + s] = (bf16)v;
                } else if (MODE == M_GELU) {
                    float xg = v + bias[col];
                    Cb[(long long)row * N + col] = (bf16)(xg / (1.f + __expf(-1.702f * xg)));
                } else if (MODE == M_RESID) {
                    long long idx = (long long)row * N + col;
                    Cf[idx] += v + bias[col];
                } else if (MODE == M_WM) {
                    Cb[(long long)bz * batchC + (long long)row * N + col] = (bf16)v;
                } else { // M_OUT (fp32 + bias)
                    Cf[(long long)row * N + col] = v + bias[col];
                }
            }
        }
    }
}

// ---------------------------------------------------------------------------
// 64x128 tile GEMM — BARRIER-FREE wave-local pipeline. Each wave stages its
// own A-slice (32x32) + B-slice (64x32) into PRIVATE LDS (3 buffers, 2
// ahead), ordered only by its own vmcnt. Zero s_barrier: waves self-pace, so
// per-K-step rendezvous stalls (the invariant across R5-R8's ~88us plateau)
// vanish. LDS: 4 waves x 3 bufs x 6KB = 72KB -> 2 blocks/CU (8 indep waves).
// ---------------------------------------------------------------------------
template<int MODE>
__global__ __launch_bounds__(256)
void gemm64_k(const bf16* __restrict__ A, const bf16* __restrict__ B,
              int M, int N, int K,
              long long batchA, long long batchB, long long batchC,
              const float* __restrict__ bias,
              bf16* __restrict__ Cb, float* __restrict__ Cf)
{
    const int bm = blockIdx.x, bn = blockIdx.y, bz = blockIdx.z;
    if (MODE == M_SCORES && 2 * bn > bm) return;     // fully-masked tile (no barrier => safe)
    int kTiles = K >> 5;
    if (MODE == M_PV) {                              // P[:,k]==0 for k>row
        int lim = 2 * bm + 2;
        if (lim < kTiles) kTiles = lim;
    }

    const int tid = threadIdx.x, wid = tid >> 6, lane = tid & 63;
    const bf16* Ab = A + (long long)bz * batchA + (long long)bm * 64 * K;
    const bf16* Bb = B + (long long)bz * batchB + (long long)bn * 128 * K;

    extern __shared__ __align__(16) bf16 smem[];   // 36864 elems = 72KB
    bf16* wbase = smem + wid * 9216;               // per-wave: 3 bufs x 3072

    const int wr = wid >> 1, wc = wid & 1;

    // per-lane global src offsets (row = lane>>2 within 16-row group, col = (lane&3)*8)
    const long long sgo = (long long)(lane >> 2) * K + (lane & 3) * 8;
    const bf16* gaw = Ab + (long long)(wr * 32) * K + sgo;
    const bf16* gbw = Bb + (long long)(wc * 64) * K + sgo;

    auto stage = [&](int buf, int kt) {
        bf16* d = wbase + buf * 3072;               // [A 1024 | B 2048]
        const bf16* ga = gaw + (long long)kt * 32;
        const bf16* gb = gbw + (long long)kt * 32;
        gload_lds16(ga,            d);              // A rows  0-15
        gload_lds16(ga + 16LL * K, d + 512);        // A rows 16-31
        gload_lds16(gb,            d + 1024);       // B rows  0-15
        gload_lds16(gb + 16LL * K, d + 1536);       // B rows 16-31
        gload_lds16(gb + 32LL * K, d + 2048);       // B rows 32-47
        gload_lds16(gb + 48LL * K, d + 2560);       // B rows 48-63
    };

    f32x4 acc[2][4];
#pragma unroll
    for (int m = 0; m < 2; ++m)
#pragma unroll
        for (int n = 0; n < 4; ++n) acc[m][n] = (f32x4){0.f, 0.f, 0.f, 0.f};

    stage(0, 0);
    if (kTiles > 1) stage(1, 1);

    const int l15 = lane & 15, koff = (lane >> 4) * 8;

    for (int kt = 0; kt < kTiles; ++kt) {
        // wave-local wait: kt's 6 loads landed; kt+1's 6 may remain in flight
        if (kt + 1 < kTiles) asm volatile("s_waitcnt vmcnt(6)" ::: "memory");
        else                 asm volatile("s_waitcnt vmcnt(0)" ::: "memory");
        // formal same-wave ordering: prior ds_reads drained before overwrite
        asm volatile("s_waitcnt lgkmcnt(0)" ::: "memory");
        if (kt + 2 < kTiles) stage((kt + 2) % 3, kt + 2);

        const bf16* d = wbase + (kt % 3) * 3072;
        bf16x8 af[2], bfr[4];
#pragma unroll
        for (int m = 0; m < 2; ++m)
            af[m] = *(const bf16x8*)&d[(m * 16 + l15) * 32 + koff];
#pragma unroll
        for (int n = 0; n < 4; ++n)
            bfr[n] = *(const bf16x8*)&d[1024 + (n * 16 + l15) * 32 + koff];
#pragma unroll
        for (int m = 0; m < 2; ++m)
#pragma unroll
            for (int n = 0; n < 4; ++n)
                acc[m][n] = __builtin_amdgcn_mfma_f32_16x16x32_bf16(af[m], bfr[n], acc[m][n], 0, 0, 0);
    }

    const int cr0 = bm * 64 + wr * 32 + (lane >> 4) * 4;
    const int cc0 = bn * 128 + wc * 64 + l15;
#pragma unroll
    for (int m = 0; m < 2; ++m) {
#pragma unroll
        for (int n = 0; n < 4; ++n) {
            const int col = cc0 + n * 16;
#pragma unroll
            for (int r = 0; r < 4; ++r) {
                const int row = cr0 + m * 16 + r;
                float v = acc[m][n][r];
                if (MODE == M_SCORES || MODE == M_PV) {
                    Cb[(long long)bz * batchC + (long long)row * N + col] = (bf16)v;
                } else if (MODE == M_RESID) {
                    long long idx = (long long)row * N + col;
                    Cf[idx] += v + bias[col];
                } else { // M_OUT (fp32 + bias)
                    Cf[(long long)row * N + col] = v + bias[col];
                }
            }
        }
    }
}

// ---------------------------------------------------------------------------
__global__ __launch_bounds__(256)
void cvt_bf16_k(const float* __restrict__ in, bf16* __restrict__ out, int n4)
{
    int i = blockIdx.x * 256 + threadIdx.x;
    if (i >= n4) return;
    float4 f = ((const float4*)in)[i];
    bf16x4 o = { (bf16)f.x, (bf16)f.y, (bf16)f.z, (bf16)f.w };
    ((bf16x4*)out)[i] = o;
}

// out[l][c][r] = (bf16) in[l][r][c]   (n x n per layer, n mult of 32)
__global__ __launch_bounds__(256)
void transpose_cvt_k(const float* __restrict__ in, bf16* __restrict__ out, int n)
{
    __shared__ float t[32][33];
    const int l = blockIdx.z;
    const int r0 = blockIdx.y * 32, c0 = blockIdx.x * 32;
    const float* src = in + (long long)l * n * n;
    bf16* dst = out + (long long)l * n * n;
    const int tx = threadIdx.x & 31, ty = threadIdx.x >> 5;   // 32x8
#pragma unroll
    for (int i = 0; i < 32; i += 8)
        t[ty + i][tx] = src[(long long)(r0 + ty + i) * n + c0 + tx];
    __syncthreads();
#pragma unroll
    for (int i = 0; i < 32; i += 8)
        dst[(long long)(c0 + ty + i) * n + r0 + tx] = (bf16)t[tx][ty + i];
}

// merged bias: bm[l][a] = sum_j o2w[l][a][j]*o1b[l][j] + o2b[l][a]; one wave per (l,a)
__global__ __launch_bounds__(256)
void bias_merge_k(const float* __restrict__ o2w, const float* __restrict__ o1b,
                  const float* __restrict__ o2b, float* __restrict__ bm, int total)
{
    const int wid = threadIdx.x >> 6, lane = threadIdx.x & 63;
    const int idx = blockIdx.x * 4 + wid;
    if (idx >= total) return;
    const int l = idx / 768, a = idx - l * 768;
    const float* wrow = o2w + ((long long)l * 768 + a) * 768;
    const float* brow = o1b + (long long)l * 768;
    float s = 0.f;
#pragma unroll
    for (int j = 0; j < 12; ++j) {
        int c = j * 64 + lane;
        s += wrow[c] * brow[c];
    }
#pragma unroll
    for (int o = 32; o; o >>= 1) s += __shfl_down(s, o);
    if (lane == 0) bm[idx] = s + o2b[(long long)l * 768 + a];
}

__global__ __launch_bounds__(256)
void cond_proj_k(const float* __restrict__ label, const float* __restrict__ sw,
                 const float* __restrict__ bw, float* __restrict__ scale,
                 float* __restrict__ bias, int total)
{
    int idx = blockIdx.x * 256 + threadIdx.x;
    if (idx >= total) return;
    int l = idx / 6144;
    int rem = idx - l * 6144;
    int b = rem / 768, d = rem - (rem / 768) * 768;
    const float* lab = label + b * 17;
    const float* swp = sw + ((long long)l * 768 + d) * 17;
    const float* bwp = bw + ((long long)l * 768 + d) * 17;
    float s = 0.f, bb = 0.f;
#pragma unroll
    for (int c = 0; c < 17; ++c) { float lv = lab[c]; s += lv * swp[c]; bb += lv * bwp[c]; }
    scale[idx] = s;
    bias[idx]  = bb;
}

// h[b,s,:] = (s==0 ? sos : xe[b,s-1,:]) + pos_bias(s)
__global__ __launch_bounds__(256)
void shift_pos_k(const float* __restrict__ xe, const float* __restrict__ sos,
                 const float* __restrict__ p0, const float* __restrict__ p1,
                 const float* __restrict__ p2, float* __restrict__ h)
{
    const int s = blockIdx.x, b = blockIdx.y;
    const int i0 = s >> 8, i1 = (s >> 4) & 15, i2 = s & 15;
    const float* xr = xe + ((long long)b * 1024 + (s - 1)) * 768;
#pragma unroll
    for (int j = 0; j < 3; ++j) {
        const int d = j * 256 + threadIdx.x;
        float v = (s == 0) ? sos[d] : xr[d];
        float pbv = (d < 256) ? p0[i0 * 256 + d]
                  : (d < 512) ? p1[i1 * 256 + (d - 256)]
                              : p2[i2 * 256 + (d - 512)];
        h[((long long)b * 1024 + s) * 768 + d] = v + pbv;
    }
}

__global__ __launch_bounds__(256)
void cond_ln_k(const float* __restrict__ h, const float* __restrict__ scale,
               const float* __restrict__ bias, bf16* __restrict__ out)
{
    const long long row = (long long)blockIdx.y * 1024 + blockIdx.x;
    const int b = blockIdx.y;
    const float* hr = h + row * 768;
    float v[3], sum = 0.f, sq = 0.f;
#pragma unroll
    for (int j = 0; j < 3; ++j) {
        v[j] = hr[j * 256 + threadIdx.x];
        sum += v[j]; sq += v[j] * v[j];
    }
    __shared__ float sm[8];
#pragma unroll
    for (int o = 32; o; o >>= 1) { sum += __shfl_down(sum, o); sq += __shfl_down(sq, o); }
    const int wid = threadIdx.x >> 6;
    if ((threadIdx.x & 63) == 0) { sm[wid] = sum; sm[4 + wid] = sq; }
    __syncthreads();
    sum = sm[0] + sm[1] + sm[2] + sm[3];
    sq  = sm[4] + sm[5] + sm[6] + sm[7];
    const float mean = sum * (1.f / 768.f);
    const float var  = sq * (1.f / 768.f) - mean * mean;
    const float rs   = rsqrtf(var + 1e-6f);
    const float* sc = scale + (long long)b * 768;
    const float* bi = bias  + (long long)b * 768;
    bf16* orow = out + row * 768;
#pragma unroll
    for (int j = 0; j < 3; ++j) {
        const int d = j * 256 + threadIdx.x;
        orow[d] = (bf16)((v[j] - mean) * rs * (1.f + sc[d]) + bi[d]);
    }
}

// causal softmax over row i. Touches only cols < ceil64(i+1).
__global__ __launch_bounds__(256)
void softmax_k(bf16* __restrict__ P)
{
    const int i = blockIdx.x, b = blockIdx.y;
    bf16* row = P + ((long long)b * 1024 + i) * 1024;
    const int len = i + 1;
    const int lim = (i | 63) + 1;          // 64-col boundary PV can read up to
    float v[4], mx = -1e30f;
#pragma unroll
    for (int j = 0; j < 4; ++j) {
        int c = j * 256 + threadIdx.x;
        v[j] = (c < len) ? (float)row[c] : -1e30f;
        mx = fmaxf(mx, v[j]);
    }
    __shared__ float sm[8];
#pragma unroll
    for (int o = 32; o; o >>= 1) mx = fmaxf(mx, __shfl_down(mx, o));
    const int wid = threadIdx.x >> 6;
    if ((threadIdx.x & 63) == 0) sm[wid] = mx;
    __syncthreads();
    mx = fmaxf(fmaxf(sm[0], sm[1]), fmaxf(sm[2], sm[3]));
    float s = 0.f;
#pragma unroll
    for (int j = 0; j < 4; ++j) {
        v[j] = __expf(v[j] - mx);
        s += ((j * 256 + threadIdx.x) < len) ? v[j] : 0.f;
    }
#pragma unroll
    for (int o = 32; o; o >>= 1) s += __shfl_down(s, o);
    if ((threadIdx.x & 63) == 0) sm[4 + wid] = s;
    __syncthreads();
    s = sm[4] + sm[5] + sm[6] + sm[7];
    const float inv = 1.f / s;
#pragma unroll
    for (int j = 0; j < 4; ++j) {
        int c = j * 256 + threadIdx.x;
        if (c < lim) row[c] = (c < len) ? (bf16)(v[j] * inv) : (bf16)0.f;
    }
}

__global__ __launch_bounds__(256)
void fill_k(float* o, int n, float v)
{
    int i = blockIdx.x * 256 + threadIdx.x;
    if (i < n) o[i] = v;
}

// ---------------------------------------------------------------------------
extern "C" void kernel_launch(void* const* d_in, const int* in_sizes, int n_in,
                              void* d_out, int out_size, void* d_ws, size_t ws_size,
                              hipStream_t stream)
{
    (void)in_sizes; (void)n_in;
    const float* x     = (const float*)d_in[0];
    const float* label = (const float*)d_in[2];
    const float* dw    = (const float*)d_in[3];
    const float* db    = (const float*)d_in[4];
    const float* sos   = (const float*)d_in[5];
    const float* p0    = (const float*)d_in[6];
    const float* p1    = (const float*)d_in[7];
    const float* p2    = (const float*)d_in[8];
    const float* ln1sw = (const float*)d_in[9];
    const float* ln1bw = (const float*)d_in[10];
    const float* qkvw  = (const float*)d_in[11];
    const float* qkvb  = (const float*)d_in[12];
    const float* ao1w  = (const float*)d_in[13];
    const float* ao1b  = (const float*)d_in[14];
    const float* ao2w  = (const float*)d_in[15];
    const float* ao2b  = (const float*)d_in[16];
    const float* ln2sw = (const float*)d_in[17];
    const float* ln2bw = (const float*)d_in[18];
    const float* m1w   = (const float*)d_in[19];
    const float* m1b   = (const float*)d_in[20];
    const float* m2w   = (const float*)d_in[21];
    const float* m2b   = (const float*)d_in[22];
    const float* lnfsw = (const float*)d_in[23];
    const float* lnfbw = (const float*)d_in[24];
    const float* outw  = (const float*)d_in[25];
    const float* outb  = (const float*)d_in[26];
    float* out = (float*)d_out;

    char* p = (char*)d_ws;
    auto alloc = [&](size_t bytes) { void* r = (void*)p; p += (bytes + 255) & ~(size_t)255; return r; };
    float* h    = (float*)alloc(8192LL * 768 * 4);
    bf16*  hn   = (bf16*) alloc(8192LL * 768 * 2);
    bf16*  q    = (bf16*) alloc(8192LL * 768 * 2);
    bf16*  kbuf = (bf16*) alloc(8192LL * 768 * 2);
    bf16*  vT   = (bf16*) alloc(8192LL * 768 * 2);   // [B,768,1024]
    bf16*  P    = (bf16*) alloc(8LL * 1024 * 1024 * 2);
    bf16*  attn = (bf16*) alloc(8192LL * 768 * 2);
    bf16*  mb   = (bf16*) alloc(8192LL * 3072 * 2);
    bf16*  wout = (bf16*) alloc(1024LL * 768 * 2);
    bf16*  wmA  = (bf16*) alloc(12LL * 768 * 768 * 2);   // merged o2@o1, bf16
    float* bmA  = (float*)alloc(12LL * 768 * 4);         // merged o-bias
    float* s1   = (float*)alloc(12LL * 8 * 768 * 4);
    float* b1   = (float*)alloc(12LL * 8 * 768 * 4);
    float* s2   = (float*)alloc(12LL * 8 * 768 * 4);
    float* b2   = (float*)alloc(12LL * 8 * 768 * 4);
    float* sf   = (float*)alloc(8LL * 768 * 4);
    float* bfb  = (float*)alloc(8LL * 768 * 4);

    size_t base_needed = (size_t)(p - (char*)d_ws);
    if (base_needed + 16LL * 1024 * 1024 > ws_size) {
        fill_k<<<(out_size + 255) / 256, 256, 0, stream>>>(out, out_size, 1e9f);
        return;
    }

    // weight conversion: all-layers-at-once if ws allows, else per-layer
    const long long SZ_QKV = 2304LL * 768, SZ_O = 768LL * 768, SZ_M = 3072LL * 768;
    size_t all_bytes = (size_t)(12 * (SZ_QKV + 2 * SZ_M)) * 2;
    bool allw = ((size_t)(p - (char*)d_ws) + all_bytes + 4096 <= ws_size);

    bf16 *wqkvA, *wm1A, *wm2A;
    if (allw) {
        wqkvA = (bf16*)alloc(12 * SZ_QKV * 2);
        wm1A  = (bf16*)alloc(12 * SZ_M * 2);
        wm2A  = (bf16*)alloc(12 * SZ_M * 2);
    } else {
        wqkvA = (bf16*)alloc(SZ_QKV * 2);
        wm1A  = (bf16*)alloc(SZ_M * 2);
        wm2A  = (bf16*)alloc(SZ_M * 2);
    }

    // one-time scratch aliased onto regions unused until the layer loop:
    bf16*  xbf   = (bf16*)P;
    bf16*  dwbf  = (bf16*)P + 524288;
    bf16*  wo2bf = (bf16*)P + 1048576;
    float* xe    = (float*)mb;
    bf16*  o1t   = mb + 12582912;

    // --- one-time precompute ---
    cvt_bf16_k<<<1024 * 768 / 4 / 256, 256, 0, stream>>>(outw, wout, 1024 * 768 / 4);
    cond_proj_k<<<(12 * 8 * 768 + 255) / 256, 256, 0, stream>>>(label, ln1sw, ln1bw, s1, b1, 12 * 8 * 768);
    cond_proj_k<<<(12 * 8 * 768 + 255) / 256, 256, 0, stream>>>(label, ln2sw, ln2bw, s2, b2, 12 * 8 * 768);
    cond_proj_k<<<(8 * 768 + 255) / 256, 256, 0, stream>>>(label, lnfsw, lnfbw, sf, bfb, 8 * 768);

    if (allw) {
        cvt_bf16_k<<<(int)(12 * SZ_QKV / 4 / 256), 256, 0, stream>>>(qkvw, wqkvA, (int)(12 * SZ_QKV / 4));
        cvt_bf16_k<<<(int)(12 * SZ_M / 4 / 256),   256, 0, stream>>>(m1w,  wm1A,  (int)(12 * SZ_M / 4));
        cvt_bf16_k<<<(int)(12 * SZ_M / 4 / 256),   256, 0, stream>>>(m2w,  wm2A,  (int)(12 * SZ_M / 4));
    }

    // merged out-proj: Wm[l] = o2[l] @ o1[l]  (bf16), bm[l] = o2[l]@o1b[l] + o2b[l]
    cvt_bf16_k<<<(int)(12 * SZ_O / 4 / 256), 256, 0, stream>>>(ao2w, wo2bf, (int)(12 * SZ_O / 4));
    transpose_cvt_k<<<dim3(24, 24, 12), 256, 0, stream>>>(ao1w, o1t, 768);
    gemm_k<M_WM><<<dim3(6, 6, 12), 256, 49152, stream>>>(
        wo2bf, o1t, 768, 768, 768, SZ_O, SZ_O, SZ_O,
        nullptr, wmA, nullptr, nullptr, nullptr, nullptr);
    bias_merge_k<<<(12 * 768 + 3) / 4, 256, 0, stream>>>(ao2w, ao1b, ao2b, bmA, 12 * 768);

    // embed: x->bf16, xe = x @ dw^T + db (fp32), then shift+pos
    cvt_bf16_k<<<8192 * 64 / 4 / 256, 256, 0, stream>>>(x, xbf, 8192 * 64 / 4);
    cvt_bf16_k<<<768 * 64 / 4 / 256, 256, 0, stream>>>(dw, dwbf, 768 * 64 / 4);
    gemm_k<M_OUT><<<dim3(64, 6, 1), 256, 49152, stream>>>(
        xbf, dwbf, 8192, 768, 64, 0, 0, 0, db, nullptr, xe, nullptr, nullptr, nullptr);
    shift_pos_k<<<dim3(1024, 8), 256, 0, stream>>>(xe, sos, p0, p1, p2, h);

    for (int l = 0; l < 12; ++l) {
        bf16 *wqkv, *wm1, *wm2;
        if (allw) {
            wqkv = wqkvA + (long long)l * SZ_QKV;
            wm1  = wm1A  + (long long)l * SZ_M;
            wm2  = wm2A  + (long long)l * SZ_M;
        } else {
            wqkv = wqkvA; wm1 = wm1A; wm2 = wm2A;
            cvt_bf16_k<<<(int)(SZ_QKV / 4 / 256), 256, 0, stream>>>(qkvw + (long long)l * SZ_QKV, wqkv, (int)(SZ_QKV / 4));
            cvt_bf16_k<<<(int)(SZ_M / 4 / 256),   256, 0, stream>>>(m1w  + (long long)l * SZ_M,   wm1,  (int)(SZ_M / 4));
            cvt_bf16_k<<<(int)(SZ_M / 4 / 256),   256, 0, stream>>>(m2w  + (long long)l * SZ_M,   wm2,  (int)(SZ_M / 4));
        }

        cond_ln_k<<<dim3(1024, 8), 256, 0, stream>>>(h, s1 + (long long)l * 6144, b1 + (long long)l * 6144, hn);

        gemm_k<M_QKV><<<dim3(64, 18, 1), 256, 49152, stream>>>(
            hn, wqkv, 8192, 2304, 768, 0, 0, 0,
            qkvb + (long long)l * 2304, nullptr, nullptr, q, kbuf, vT);

        gemm64_k<M_SCORES><<<dim3(16, 8, 8), 256, 73728, stream>>>(
            q, kbuf, 1024, 1024, 768, 1024LL * 768, 1024LL * 768, 1024LL * 1024,
            nullptr, P, nullptr);

        softmax_k<<<dim3(1024, 8), 256, 0, stream>>>(P);

        gemm64_k<M_PV><<<dim3(16, 6, 8), 256, 73728, stream>>>(
            P, vT, 1024, 768, 1024, 1024LL * 1024, 768LL * 1024, 1024LL * 768,
            nullptr, attn, nullptr);

        // merged out-proj (o2@o1 fused), residual add into h
        gemm64_k<M_RESID><<<dim3(128, 6, 1), 256, 73728, stream>>>(
            attn, wmA + (long long)l * SZ_O, 8192, 768, 768, 0, 0, 0,
            bmA + (long long)l * 768, nullptr, h);

        cond_ln_k<<<dim3(1024, 8), 256, 0, stream>>>(h, s2 + (long long)l * 6144, b2 + (long long)l * 6144, hn);

        gemm_k<M_GELU><<<dim3(64, 24, 1), 256, 49152, stream>>>(
            hn, wm1, 8192, 3072, 768, 0, 0, 0,
            m1b + (long long)l * 3072, mb, nullptr, nullptr, nullptr, nullptr);

        // mlp2, residual add into h
        gemm64_k<M_RESID><<<dim3(128, 6, 1), 256, 73728, stream>>>(
            mb, wm2, 8192, 768, 3072, 0, 0, 0,
            m2b + (long long)l * 768, nullptr, h);
    }

    cond_ln_k<<<dim3(1024, 8), 256, 0, stream>>>(h, sf, bfb, hn);
    gemm64_k<M_OUT><<<dim3(128, 8, 1), 256, 73728, stream>>>(
        hn, wout, 8192, 1024, 768, 0, 0, 0,
        outb, nullptr, out);
}

// Round 10
// 4408.410 us; speedup vs baseline: 1.2133x; 1.0489x over previous
//
#include <hip/hip_runtime.h>

typedef __bf16 bf16;
typedef __bf16 bf16x8 __attribute__((ext_vector_type(8)));
typedef __bf16 bf16x4 __attribute__((ext_vector_type(4)));
typedef float  f32x4  __attribute__((ext_vector_type(4)));

#define DEV __device__ __forceinline__

// async global->LDS, 16B per lane; lds dest must be wave-uniform base (HW adds lane*16)
DEV void gload_lds16(const bf16* g, bf16* l) {
    __builtin_amdgcn_global_load_lds(
        (__attribute__((address_space(1))) void*)g,
        (__attribute__((address_space(3))) void*)l, 16, 0, 0);
}

// lgkmcnt(0) first: wave's own ds_reads complete before the barrier, so the
// next buffer-overwrite (gload_lds) can never race an in-flight read.
DEV void barrier_raw() {
    asm volatile("s_waitcnt lgkmcnt(0)" ::: "memory");
    __builtin_amdgcn_s_barrier();
    asm volatile("" ::: "memory");
}

enum { M_QKV, M_SCORES, M_PV, M_RESID, M_GELU, M_OUT, M_WM };

// ---------------------------------------------------------------------------
// 128x128 tile GEMM (R7 form): A+B in LDS, 3-buffer 2-ahead counted-vmcnt.
// C[m,n] = sum_k A[m,k]*B[n,k]; A:[M,K], B:[N,K] bf16 row-major. LDS 48KB.
// ---------------------------------------------------------------------------
template<int MODE>
__global__ __launch_bounds__(256)
void gemm_k(const bf16* __restrict__ A, const bf16* __restrict__ B,
            int M, int N, int K,
            long long batchA, long long batchB, long long batchC,
            const float* __restrict__ bias,
            bf16* __restrict__ Cb, float* __restrict__ Cf,
            bf16* __restrict__ qp, bf16* __restrict__ kp, bf16* __restrict__ vp)
{
    const int bm = blockIdx.x, bn = blockIdx.y, bz = blockIdx.z;
    const int kTiles = K >> 5;

    const int tid = threadIdx.x, wid = tid >> 6, lane = tid & 63;
    const bf16* Ab = A + (long long)bz * batchA + (long long)bm * 128 * K;
    const bf16* Bb = B + (long long)bz * batchB + (long long)bn * 128 * K;

    extern __shared__ __align__(16) bf16 smem[];   // 24576 elems = 48KB
    bf16* sA = smem;            // [3][4096]
    bf16* sB = smem + 12288;    // [3][4096]

    const int srow = wid * 16 + (lane >> 2);
    const int scol = (lane & 3) * 8;
    const long long aoff = (long long)srow * K + scol;

    auto stage = [&](int buf, int kt) {
        const bf16* ga = Ab + (long long)kt * 32;
        const bf16* gb = Bb + (long long)kt * 32;
        bf16* a = sA + buf * 4096;
        bf16* b = sB + buf * 4096;
        gload_lds16(ga + aoff,            a + (wid * 16) * 32);
        gload_lds16(ga + aoff + 64LL * K, a + (64 + wid * 16) * 32);
        gload_lds16(gb + aoff,            b + (wid * 16) * 32);
        gload_lds16(gb + aoff + 64LL * K, b + (64 + wid * 16) * 32);
    };

    f32x4 acc[4][4];
#pragma unroll
    for (int m = 0; m < 4; ++m)
#pragma unroll
        for (int n = 0; n < 4; ++n) acc[m][n] = (f32x4){0.f, 0.f, 0.f, 0.f};

    const int npre = kTiles < 2 ? kTiles : 2;
    for (int t = 0; t < npre; ++t) stage(t, t);

    const int wr = wid >> 1, wc = wid & 1;
    const int arow = wr * 64 + (lane & 15);
    const int brow = wc * 64 + (lane & 15);
    const int koff = (lane >> 4) * 8;

    int cur = 0;
    for (int kt = 0; kt < kTiles; ++kt) {
        if (kt + 1 < kTiles) asm volatile("s_waitcnt vmcnt(4)" ::: "memory");
        else                 asm volatile("s_waitcnt vmcnt(0)" ::: "memory");
        barrier_raw();   // all waves: stage(kt) visible; iter kt-1 reads done
        if (kt + 2 < kTiles) {
            int ib = cur - 1; if (ib < 0) ib = 2;   // (cur+2)%3
            stage(ib, kt + 2);
        }

        const bf16* a = sA + cur * 4096;
        const bf16* b = sB + cur * 4096;
        bf16x8 af[4], bfr[4];
#pragma unroll
        for (int m = 0; m < 4; ++m)
            af[m] = *(const bf16x8*)&a[(arow + m * 16) * 32 + koff];
#pragma unroll
        for (int n = 0; n < 4; ++n)
            bfr[n] = *(const bf16x8*)&b[(brow + n * 16) * 32 + koff];
#pragma unroll
        for (int m = 0; m < 4; ++m)
#pragma unroll
            for (int n = 0; n < 4; ++n)
                acc[m][n] = __builtin_amdgcn_mfma_f32_16x16x32_bf16(af[m], bfr[n], acc[m][n], 0, 0, 0);

        cur = (cur == 2) ? 0 : cur + 1;
    }

    // C/D layout: col = lane&15, row = (lane>>4)*4 + r   [learn_hip m89]
    const int cr0 = bm * 128 + wr * 64 + (lane >> 4) * 4;
    const int cc0 = bn * 128 + wc * 64 + (lane & 15);
#pragma unroll
    for (int m = 0; m < 4; ++m) {
#pragma unroll
        for (int n = 0; n < 4; ++n) {
            const int col = cc0 + n * 16;
#pragma unroll
            for (int r = 0; r < 4; ++r) {
                const int row = cr0 + m * 16 + r;
                float v = acc[m][n][r];
                if (MODE == M_GELU) {
                    float xg = v + bias[col];
                    Cb[(long long)row * N + col] = (bf16)(xg / (1.f + __expf(-1.702f * xg)));
                } else if (MODE == M_RESID) {
                    long long idx = (long long)row * N + col;
                    Cf[idx] += v + bias[col];
                } else if (MODE == M_WM) {
                    Cb[(long long)bz * batchC + (long long)row * N + col] = (bf16)v;
                } else { // M_OUT (fp32 + bias)
                    Cf[(long long)row * N + col] = v + bias[col];
                }
            }
        }
    }
}

// ---------------------------------------------------------------------------
// 128x256 tile GEMM — same 3-buffer 2-ahead skeleton, 2x MFMA per barrier
// (32/wave) to amortize the rendezvous stall (the R5-R9 invariant). For the
// fat deep-grid GEMMs: qkv (grid 576), mlp1 (grid 768). LDS 72KB -> 2/CU.
// ---------------------------------------------------------------------------
template<int MODE>
__global__ __launch_bounds__(256)
void gemm_w(const bf16* __restrict__ A, const bf16* __restrict__ B,
            int N, int K,
            const float* __restrict__ bias,
            bf16* __restrict__ Cb,
            bf16* __restrict__ qp, bf16* __restrict__ kp, bf16* __restrict__ vp)
{
    const int bm = blockIdx.x, bn = blockIdx.y;
    const int kTiles = K >> 5;

    const int tid = threadIdx.x, wid = tid >> 6, lane = tid & 63;
    const bf16* Ab = A + (long long)bm * 128 * K;
    const bf16* Bb = B + (long long)bn * 256 * K;

    extern __shared__ __align__(16) bf16 smem[];   // 36864 elems = 72KB
    bf16* sA = smem;            // [3][4096]  (128 x 32)
    bf16* sB = smem + 12288;    // [3][8192]  (256 x 32)

    const int srow = wid * 16 + (lane >> 2);
    const int scol = (lane & 3) * 8;
    const long long aoff = (long long)srow * K + scol;

    auto stage = [&](int buf, int kt) {          // 6 gload calls
        const bf16* ga = Ab + (long long)kt * 32;
        const bf16* gb = Bb + (long long)kt * 32;
        bf16* a = sA + buf * 4096;
        bf16* b = sB + buf * 8192;
        gload_lds16(ga + aoff,             a + (wid * 16) * 32);
        gload_lds16(ga + aoff + 64LL * K,  a + (64 + wid * 16) * 32);
        gload_lds16(gb + aoff,             b + (wid * 16) * 32);
        gload_lds16(gb + aoff + 64LL * K,  b + (64 + wid * 16) * 32);
        gload_lds16(gb + aoff + 128LL * K, b + (128 + wid * 16) * 32);
        gload_lds16(gb + aoff + 192LL * K, b + (192 + wid * 16) * 32);
    };

    f32x4 acc[4][8];
#pragma unroll
    for (int m = 0; m < 4; ++m)
#pragma unroll
        for (int n = 0; n < 8; ++n) acc[m][n] = (f32x4){0.f, 0.f, 0.f, 0.f};

    const int npre = kTiles < 2 ? kTiles : 2;
    for (int t = 0; t < npre; ++t) stage(t, t);

    const int wr = wid >> 1, wc = wid & 1;
    const int arow = wr * 64 + (lane & 15);
    const int brow = wc * 128 + (lane & 15);
    const int koff = (lane >> 4) * 8;

    int cur = 0;
    for (int kt = 0; kt < kTiles; ++kt) {
        if (kt + 1 < kTiles) asm volatile("s_waitcnt vmcnt(6)" ::: "memory");
        else                 asm volatile("s_waitcnt vmcnt(0)" ::: "memory");
        barrier_raw();
        if (kt + 2 < kTiles) {
            int ib = cur - 1; if (ib < 0) ib = 2;   // (cur+2)%3
            stage(ib, kt + 2);
        }

        const bf16* a = sA + cur * 4096;
        const bf16* b = sB + cur * 8192;
        bf16x8 af[4], bfr[8];
#pragma unroll
        for (int m = 0; m < 4; ++m)
            af[m] = *(const bf16x8*)&a[(arow + m * 16) * 32 + koff];
#pragma unroll
        for (int n = 0; n < 8; ++n)
            bfr[n] = *(const bf16x8*)&b[(brow + n * 16) * 32 + koff];
#pragma unroll
        for (int m = 0; m < 4; ++m)
#pragma unroll
            for (int n = 0; n < 8; ++n)
                acc[m][n] = __builtin_amdgcn_mfma_f32_16x16x32_bf16(af[m], bfr[n], acc[m][n], 0, 0, 0);

        cur = (cur == 2) ? 0 : cur + 1;
    }

    const int cr0 = bm * 128 + wr * 64 + (lane >> 4) * 4;
    const int cc0 = bn * 256 + wc * 128 + (lane & 15);
#pragma unroll
    for (int m = 0; m < 4; ++m) {
#pragma unroll
        for (int n = 0; n < 8; ++n) {
            const int col = cc0 + n * 16;
#pragma unroll
            for (int r = 0; r < 4; ++r) {
                const int row = cr0 + m * 16 + r;
                float v = acc[m][n][r];
                if (MODE == M_QKV) {
                    v += bias[col];
                    int hd = col / 192, rr = col % 192;
                    int b2 = row >> 10, s = row & 1023;
                    if (rr < 64)
                        qp[(long long)row * 768 + hd * 64 + rr] = (bf16)(v * 0.03608439182435161f);
                    else if (rr < 128)
                        kp[(long long)row * 768 + hd * 64 + (rr - 64)] = (bf16)v;
                    else
                        vp[((long long)b2 * 768 + hd * 64 + (rr - 128)) * 1024 + s] = (bf16)v;
                } else { // M_GELU
                    float xg = v + bias[col];
                    Cb[(long long)row * N + col] = (bf16)(xg / (1.f + __expf(-1.702f * xg)));
                }
            }
        }
    }
}

// ---------------------------------------------------------------------------
// 64x128 tile GEMM (R7 form), 3-buffer 2-ahead, shared LDS 36KB -> 4/CU.
// For scores/PV (causal granularity), mlp2, o-merged, final out.
// ---------------------------------------------------------------------------
template<int MODE>
__global__ __launch_bounds__(256)
void gemm64_k(const bf16* __restrict__ A, const bf16* __restrict__ B,
              int M, int N, int K,
              long long batchA, long long batchB, long long batchC,
              const float* __restrict__ bias,
              bf16* __restrict__ Cb, float* __restrict__ Cf)
{
    const int bm = blockIdx.x, bn = blockIdx.y, bz = blockIdx.z;
    if (MODE == M_SCORES && 2 * bn > bm) return;     // fully-masked tile
    int kTiles = K >> 5;
    if (MODE == M_PV) {                              // P[:,k]==0 for k>row
        int lim = 2 * bm + 2;
        if (lim < kTiles) kTiles = lim;
    }

    const int tid = threadIdx.x, wid = tid >> 6, lane = tid & 63;
    const bf16* Ab = A + (long long)bz * batchA + (long long)bm * 64 * K;
    const bf16* Bb = B + (long long)bz * batchB + (long long)bn * 128 * K;

    extern __shared__ __align__(16) bf16 smem[];   // 18432 elems = 36KB
    bf16* sA = smem;            // [3][2048]
    bf16* sB = smem + 6144;     // [3][4096]

    const int srow = wid * 16 + (lane >> 2);          // 0..63
    const int scol = (lane & 3) * 8;
    const long long aoff = (long long)srow * K + scol;

    auto stage = [&](int buf, int kt) {
        const bf16* ga = Ab + (long long)kt * 32;
        const bf16* gb = Bb + (long long)kt * 32;
        gload_lds16(ga + aoff,            sA + buf * 2048 + (wid * 16) * 32);
        gload_lds16(gb + aoff,            sB + buf * 4096 + (wid * 16) * 32);
        gload_lds16(gb + aoff + 64LL * K, sB + buf * 4096 + (64 + wid * 16) * 32);
    };

    f32x4 acc[2][4];
#pragma unroll
    for (int m = 0; m < 2; ++m)
#pragma unroll
        for (int n = 0; n < 4; ++n) acc[m][n] = (f32x4){0.f, 0.f, 0.f, 0.f};

    const int npre = kTiles < 2 ? kTiles : 2;
    for (int t = 0; t < npre; ++t) stage(t, t);

    const int wr = wid >> 1, wc = wid & 1;
    const int arow = wr * 32 + (lane & 15);
    const int brow = wc * 64 + (lane & 15);
    const int koff = (lane >> 4) * 8;

    int cur = 0;
    for (int kt = 0; kt < kTiles; ++kt) {
        if (kt + 1 < kTiles) asm volatile("s_waitcnt vmcnt(3)" ::: "memory");
        else                 asm volatile("s_waitcnt vmcnt(0)" ::: "memory");
        barrier_raw();
        if (kt + 2 < kTiles) {
            int ib = cur - 1; if (ib < 0) ib = 2;   // (cur+2)%3
            stage(ib, kt + 2);
        }

        const bf16* a = sA + cur * 2048;
        const bf16* b = sB + cur * 4096;
        bf16x8 af[2], bfr[4];
#pragma unroll
        for (int m = 0; m < 2; ++m)
            af[m] = *(const bf16x8*)&a[(arow + m * 16) * 32 + koff];
#pragma unroll
        for (int n = 0; n < 4; ++n)
            bfr[n] = *(const bf16x8*)&b[(brow + n * 16) * 32 + koff];
#pragma unroll
        for (int m = 0; m < 2; ++m)
#pragma unroll
            for (int n = 0; n < 4; ++n)
                acc[m][n] = __builtin_amdgcn_mfma_f32_16x16x32_bf16(af[m], bfr[n], acc[m][n], 0, 0, 0);

        cur = (cur == 2) ? 0 : cur + 1;
    }

    const int cr0 = bm * 64 + wr * 32 + (lane >> 4) * 4;
    const int cc0 = bn * 128 + wc * 64 + (lane & 15);
#pragma unroll
    for (int m = 0; m < 2; ++m) {
#pragma unroll
        for (int n = 0; n < 4; ++n) {
            const int col = cc0 + n * 16;
#pragma unroll
            for (int r = 0; r < 4; ++r) {
                const int row = cr0 + m * 16 + r;
                float v = acc[m][n][r];
                if (MODE == M_SCORES || MODE == M_PV) {
                    Cb[(long long)bz * batchC + (long long)row * N + col] = (bf16)v;
                } else if (MODE == M_RESID) {
                    long long idx = (long long)row * N + col;
                    Cf[idx] += v + bias[col];
                } else { // M_OUT (fp32 + bias)
                    Cf[(long long)row * N + col] = v + bias[col];
                }
            }
        }
    }
}

// ---------------------------------------------------------------------------
__global__ __launch_bounds__(256)
void cvt_bf16_k(const float* __restrict__ in, bf16* __restrict__ out, int n4)
{
    int i = blockIdx.x * 256 + threadIdx.x;
    if (i >= n4) return;
    float4 f = ((const float4*)in)[i];
    bf16x4 o = { (bf16)f.x, (bf16)f.y, (bf16)f.z, (bf16)f.w };
    ((bf16x4*)out)[i] = o;
}

// out[l][c][r] = (bf16) in[l][r][c]   (n x n per layer, n mult of 32)
__global__ __launch_bounds__(256)
void transpose_cvt_k(const float* __restrict__ in, bf16* __restrict__ out, int n)
{
    __shared__ float t[32][33];
    const int l = blockIdx.z;
    const int r0 = blockIdx.y * 32, c0 = blockIdx.x * 32;
    const float* src = in + (long long)l * n * n;
    bf16* dst = out + (long long)l * n * n;
    const int tx = threadIdx.x & 31, ty = threadIdx.x >> 5;   // 32x8
#pragma unroll
    for (int i = 0; i < 32; i += 8)
        t[ty + i][tx] = src[(long long)(r0 + ty + i) * n + c0 + tx];
    __syncthreads();
#pragma unroll
    for (int i = 0; i < 32; i += 8)
        dst[(long long)(c0 + ty + i) * n + r0 + tx] = (bf16)t[tx][ty + i];
}

// merged bias: bm[l][a] = sum_j o2w[l][a][j]*o1b[l][j] + o2b[l][a]; one wave per (l,a)
__global__ __launch_bounds__(256)
void bias_merge_k(const float* __restrict__ o2w, const float* __restrict__ o1b,
                  const float* __restrict__ o2b, float* __restrict__ bm, int total)
{
    const int wid = threadIdx.x >> 6, lane = threadIdx.x & 63;
    const int idx = blockIdx.x * 4 + wid;
    if (idx >= total) return;
    const int l = idx / 768, a = idx - l * 768;
    const float* wrow = o2w + ((long long)l * 768 + a) * 768;
    const float* brow = o1b + (long long)l * 768;
    float s = 0.f;
#pragma unroll
    for (int j = 0; j < 12; ++j) {
        int c = j * 64 + lane;
        s += wrow[c] * brow[c];
    }
#pragma unroll
    for (int o = 32; o; o >>= 1) s += __shfl_down(s, o);
    if (lane == 0) bm[idx] = s + o2b[(long long)l * 768 + a];
}

__global__ __launch_bounds__(256)
void cond_proj_k(const float* __restrict__ label, const float* __restrict__ sw,
                 const float* __restrict__ bw, float* __restrict__ scale,
                 float* __restrict__ bias, int total)
{
    int idx = blockIdx.x * 256 + threadIdx.x;
    if (idx >= total) return;
    int l = idx / 6144;
    int rem = idx - l * 6144;
    int b = rem / 768, d = rem - (rem / 768) * 768;
    const float* lab = label + b * 17;
    const float* swp = sw + ((long long)l * 768 + d) * 17;
    const float* bwp = bw + ((long long)l * 768 + d) * 17;
    float s = 0.f, bb = 0.f;
#pragma unroll
    for (int c = 0; c < 17; ++c) { float lv = lab[c]; s += lv * swp[c]; bb += lv * bwp[c]; }
    scale[idx] = s;
    bias[idx]  = bb;
}

// h[b,s,:] = (s==0 ? sos : xe[b,s-1,:]) + pos_bias(s)
__global__ __launch_bounds__(256)
void shift_pos_k(const float* __restrict__ xe, const float* __restrict__ sos,
                 const float* __restrict__ p0, const float* __restrict__ p1,
                 const float* __restrict__ p2, float* __restrict__ h)
{
    const int s = blockIdx.x, b = blockIdx.y;
    const int i0 = s >> 8, i1 = (s >> 4) & 15, i2 = s & 15;
    const float* xr = xe + ((long long)b * 1024 + (s - 1)) * 768;
#pragma unroll
    for (int j = 0; j < 3; ++j) {
        const int d = j * 256 + threadIdx.x;
        float v = (s == 0) ? sos[d] : xr[d];
        float pbv = (d < 256) ? p0[i0 * 256 + d]
                  : (d < 512) ? p1[i1 * 256 + (d - 256)]
                              : p2[i2 * 256 + (d - 512)];
        h[((long long)b * 1024 + s) * 768 + d] = v + pbv;
    }
}

__global__ __launch_bounds__(256)
void cond_ln_k(const float* __restrict__ h, const float* __restrict__ scale,
               const float* __restrict__ bias, bf16* __restrict__ out)
{
    const long long row = (long long)blockIdx.y * 1024 + blockIdx.x;
    const int b = blockIdx.y;
    const float* hr = h + row * 768;
    float v[3], sum = 0.f, sq = 0.f;
#pragma unroll
    for (int j = 0; j < 3; ++j) {
        v[j] = hr[j * 256 + threadIdx.x];
        sum += v[j]; sq += v[j] * v[j];
    }
    __shared__ float sm[8];
#pragma unroll
    for (int o = 32; o; o >>= 1) { sum += __shfl_down(sum, o); sq += __shfl_down(sq, o); }
    const int wid = threadIdx.x >> 6;
    if ((threadIdx.x & 63) == 0) { sm[wid] = sum; sm[4 + wid] = sq; }
    __syncthreads();
    sum = sm[0] + sm[1] + sm[2] + sm[3];
    sq  = sm[4] + sm[5] + sm[6] + sm[7];
    const float mean = sum * (1.f / 768.f);
    const float var  = sq * (1.f / 768.f) - mean * mean;
    const float rs   = rsqrtf(var + 1e-6f);
    const float* sc = scale + (long long)b * 768;
    const float* bi = bias  + (long long)b * 768;
    bf16* orow = out + row * 768;
#pragma unroll
    for (int j = 0; j < 3; ++j) {
        const int d = j * 256 + threadIdx.x;
        orow[d] = (bf16)((v[j] - mean) * rs * (1.f + sc[d]) + bi[d]);
    }
}

// causal softmax over row i. Touches only cols < ceil64(i+1).
__global__ __launch_bounds__(256)
void softmax_k(bf16* __restrict__ P)
{
    const int i = blockIdx.x, b = blockIdx.y;
    bf16* row = P + ((long long)b * 1024 + i) * 1024;
    const int len = i + 1;
    const int lim = (i | 63) + 1;          // 64-col boundary PV can read up to
    float v[4], mx = -1e30f;
#pragma unroll
    for (int j = 0; j < 4; ++j) {
        int c = j * 256 + threadIdx.x;
        v[j] = (c < len) ? (float)row[c] : -1e30f;
        mx = fmaxf(mx, v[j]);
    }
    __shared__ float sm[8];
#pragma unroll
    for (int o = 32; o; o >>= 1) mx = fmaxf(mx, __shfl_down(mx, o));
    const int wid = threadIdx.x >> 6;
    if ((threadIdx.x & 63) == 0) sm[wid] = mx;
    __syncthreads();
    mx = fmaxf(fmaxf(sm[0], sm[1]), fmaxf(sm[2], sm[3]));
    float s = 0.f;
#pragma unroll
    for (int j = 0; j < 4; ++j) {
        v[j] = __expf(v[j] - mx);
        s += ((j * 256 + threadIdx.x) < len) ? v[j] : 0.f;
    }
#pragma unroll
    for (int o = 32; o; o >>= 1) s += __shfl_down(s, o);
    if ((threadIdx.x & 63) == 0) sm[4 + wid] = s;
    __syncthreads();
    s = sm[4] + sm[5] + sm[6] + sm[7];
    const float inv = 1.f / s;
#pragma unroll
    for (int j = 0; j < 4; ++j) {
        int c = j * 256 + threadIdx.x;
        if (c < lim) row[c] = (c < len) ? (bf16)(v[j] * inv) : (bf16)0.f;
    }
}

__global__ __launch_bounds__(256)
void fill_k(float* o, int n, float v)
{
    int i = blockIdx.x * 256 + threadIdx.x;
    if (i < n) o[i] = v;
}

// ---------------------------------------------------------------------------
extern "C" void kernel_launch(void* const* d_in, const int* in_sizes, int n_in,
                              void* d_out, int out_size, void* d_ws, size_t ws_size,
                              hipStream_t stream)
{
    (void)in_sizes; (void)n_in;
    const float* x     = (const float*)d_in[0];
    const float* label = (const float*)d_in[2];
    const float* dw    = (const float*)d_in[3];
    const float* db    = (const float*)d_in[4];
    const float* sos   = (const float*)d_in[5];
    const float* p0    = (const float*)d_in[6];
    const float* p1    = (const float*)d_in[7];
    const float* p2    = (const float*)d_in[8];
    const float* ln1sw = (const float*)d_in[9];
    const float* ln1bw = (const float*)d_in[10];
    const float* qkvw  = (const float*)d_in[11];
    const float* qkvb  = (const float*)d_in[12];
    const float* ao1w  = (const float*)d_in[13];
    const float* ao1b  = (const float*)d_in[14];
    const float* ao2w  = (const float*)d_in[15];
    const float* ao2b  = (const float*)d_in[16];
    const float* ln2sw = (const float*)d_in[17];
    const float* ln2bw = (const float*)d_in[18];
    const float* m1w   = (const float*)d_in[19];
    const float* m1b   = (const float*)d_in[20];
    const float* m2w   = (const float*)d_in[21];
    const float* m2b   = (const float*)d_in[22];
    const float* lnfsw = (const float*)d_in[23];
    const float* lnfbw = (const float*)d_in[24];
    const float* outw  = (const float*)d_in[25];
    const float* outb  = (const float*)d_in[26];
    float* out = (float*)d_out;

    char* p = (char*)d_ws;
    auto alloc = [&](size_t bytes) { void* r = (void*)p; p += (bytes + 255) & ~(size_t)255; return r; };
    float* h    = (float*)alloc(8192LL * 768 * 4);
    bf16*  hn   = (bf16*) alloc(8192LL * 768 * 2);
    bf16*  q    = (bf16*) alloc(8192LL * 768 * 2);
    bf16*  kbuf = (bf16*) alloc(8192LL * 768 * 2);
    bf16*  vT   = (bf16*) alloc(8192LL * 768 * 2);   // [B,768,1024]
    bf16*  P    = (bf16*) alloc(8LL * 1024 * 1024 * 2);
    bf16*  attn = (bf16*) alloc(8192LL * 768 * 2);
    bf16*  mb   = (bf16*) alloc(8192LL * 3072 * 2);
    bf16*  wout = (bf16*) alloc(1024LL * 768 * 2);
    bf16*  wmA  = (bf16*) alloc(12LL * 768 * 768 * 2);   // merged o2@o1, bf16
    float* bmA  = (float*)alloc(12LL * 768 * 4);         // merged o-bias
    float* s1   = (float*)alloc(12LL * 8 * 768 * 4);
    float* b1   = (float*)alloc(12LL * 8 * 768 * 4);
    float* s2   = (float*)alloc(12LL * 8 * 768 * 4);
    float* b2   = (float*)alloc(12LL * 8 * 768 * 4);
    float* sf   = (float*)alloc(8LL * 768 * 4);
    float* bfb  = (float*)alloc(8LL * 768 * 4);

    size_t base_needed = (size_t)(p - (char*)d_ws);
    if (base_needed + 16LL * 1024 * 1024 > ws_size) {
        fill_k<<<(out_size + 255) / 256, 256, 0, stream>>>(out, out_size, 1e9f);
        return;
    }

    // weight conversion: all-layers-at-once if ws allows, else per-layer
    const long long SZ_QKV = 2304LL * 768, SZ_O = 768LL * 768, SZ_M = 3072LL * 768;
    size_t all_bytes = (size_t)(12 * (SZ_QKV + 2 * SZ_M)) * 2;
    bool allw = ((size_t)(p - (char*)d_ws) + all_bytes + 4096 <= ws_size);

    bf16 *wqkvA, *wm1A, *wm2A;
    if (allw) {
        wqkvA = (bf16*)alloc(12 * SZ_QKV * 2);
        wm1A  = (bf16*)alloc(12 * SZ_M * 2);
        wm2A  = (bf16*)alloc(12 * SZ_M * 2);
    } else {
        wqkvA = (bf16*)alloc(SZ_QKV * 2);
        wm1A  = (bf16*)alloc(SZ_M * 2);
        wm2A  = (bf16*)alloc(SZ_M * 2);
    }

    // one-time scratch aliased onto regions unused until the layer loop:
    bf16*  xbf   = (bf16*)P;
    bf16*  dwbf  = (bf16*)P + 524288;
    bf16*  wo2bf = (bf16*)P + 1048576;
    float* xe    = (float*)mb;
    bf16*  o1t   = mb + 12582912;

    // --- one-time precompute ---
    cvt_bf16_k<<<1024 * 768 / 4 / 256, 256, 0, stream>>>(outw, wout, 1024 * 768 / 4);
    cond_proj_k<<<(12 * 8 * 768 + 255) / 256, 256, 0, stream>>>(label, ln1sw, ln1bw, s1, b1, 12 * 8 * 768);
    cond_proj_k<<<(12 * 8 * 768 + 255) / 256, 256, 0, stream>>>(label, ln2sw, ln2bw, s2, b2, 12 * 8 * 768);
    cond_proj_k<<<(8 * 768 + 255) / 256, 256, 0, stream>>>(label, lnfsw, lnfbw, sf, bfb, 8 * 768);

    if (allw) {
        cvt_bf16_k<<<(int)(12 * SZ_QKV / 4 / 256), 256, 0, stream>>>(qkvw, wqkvA, (int)(12 * SZ_QKV / 4));
        cvt_bf16_k<<<(int)(12 * SZ_M / 4 / 256),   256, 0, stream>>>(m1w,  wm1A,  (int)(12 * SZ_M / 4));
        cvt_bf16_k<<<(int)(12 * SZ_M / 4 / 256),   256, 0, stream>>>(m2w,  wm2A,  (int)(12 * SZ_M / 4));
    }

    // merged out-proj: Wm[l] = o2[l] @ o1[l]  (bf16), bm[l] = o2[l]@o1b[l] + o2b[l]
    cvt_bf16_k<<<(int)(12 * SZ_O / 4 / 256), 256, 0, stream>>>(ao2w, wo2bf, (int)(12 * SZ_O / 4));
    transpose_cvt_k<<<dim3(24, 24, 12), 256, 0, stream>>>(ao1w, o1t, 768);
    gemm_k<M_WM><<<dim3(6, 6, 12), 256, 49152, stream>>>(
        wo2bf, o1t, 768, 768, 768, SZ_O, SZ_O, SZ_O,
        nullptr, wmA, nullptr, nullptr, nullptr, nullptr);
    bias_merge_k<<<(12 * 768 + 3) / 4, 256, 0, stream>>>(ao2w, ao1b, ao2b, bmA, 12 * 768);

    // embed: x->bf16, xe = x @ dw^T + db (fp32), then shift+pos
    cvt_bf16_k<<<8192 * 64 / 4 / 256, 256, 0, stream>>>(x, xbf, 8192 * 64 / 4);
    cvt_bf16_k<<<768 * 64 / 4 / 256, 256, 0, stream>>>(dw, dwbf, 768 * 64 / 4);
    gemm_k<M_OUT><<<dim3(64, 6, 1), 256, 49152, stream>>>(
        xbf, dwbf, 8192, 768, 64, 0, 0, 0, db, nullptr, xe, nullptr, nullptr, nullptr);
    shift_pos_k<<<dim3(1024, 8), 256, 0, stream>>>(xe, sos, p0, p1, p2, h);

    for (int l = 0; l < 12; ++l) {
        bf16 *wqkv, *wm1, *wm2;
        if (allw) {
            wqkv = wqkvA + (long long)l * SZ_QKV;
            wm1  = wm1A  + (long long)l * SZ_M;
            wm2  = wm2A  + (long long)l * SZ_M;
        } else {
            wqkv = wqkvA; wm1 = wm1A; wm2 = wm2A;
            cvt_bf16_k<<<(int)(SZ_QKV / 4 / 256), 256, 0, stream>>>(qkvw + (long long)l * SZ_QKV, wqkv, (int)(SZ_QKV / 4));
            cvt_bf16_k<<<(int)(SZ_M / 4 / 256),   256, 0, stream>>>(m1w  + (long long)l * SZ_M,   wm1,  (int)(SZ_M / 4));
            cvt_bf16_k<<<(int)(SZ_M / 4 / 256),   256, 0, stream>>>(m2w  + (long long)l * SZ_M,   wm2,  (int)(SZ_M / 4));
        }

        cond_ln_k<<<dim3(1024, 8), 256, 0, stream>>>(h, s1 + (long long)l * 6144, b1 + (long long)l * 6144, hn);

        gemm_w<M_QKV><<<dim3(64, 9, 1), 256, 73728, stream>>>(
            hn, wqkv, 2304, 768,
            qkvb + (long long)l * 2304, nullptr, q, kbuf, vT);

        gemm64_k<M_SCORES><<<dim3(16, 8, 8), 256, 36864, stream>>>(
            q, kbuf, 1024, 1024, 768, 1024LL * 768, 1024LL * 768, 1024LL * 1024,
            nullptr, P, nullptr);

        softmax_k<<<dim3(1024, 8), 256, 0, stream>>>(P);

        gemm64_k<M_PV><<<dim3(16, 6, 8), 256, 36864, stream>>>(
            P, vT, 1024, 768, 1024, 1024LL * 1024, 768LL * 1024, 1024LL * 768,
            nullptr, attn, nullptr);

        // merged out-proj (o2@o1 fused), residual add into h
        gemm64_k<M_RESID><<<dim3(128, 6, 1), 256, 36864, stream>>>(
            attn, wmA + (long long)l * SZ_O, 8192, 768, 768, 0, 0, 0,
            bmA + (long long)l * 768, nullptr, h);

        cond_ln_k<<<dim3(1024, 8), 256, 0, stream>>>(h, s2 + (long long)l * 6144, b2 + (long long)l * 6144, hn);

        gemm_w<M_GELU><<<dim3(64, 12, 1), 256, 73728, stream>>>(
            hn, wm1, 3072, 768,
            m1b + (long long)l * 3072, mb, nullptr, nullptr, nullptr);

        // mlp2, residual add into h
        gemm64_k<M_RESID><<<dim3(128, 6, 1), 256, 36864, stream>>>(
            mb, wm2, 8192, 768, 3072, 0, 0, 0,
            m2b + (long long)l * 768, nullptr, h);
    }

    cond_ln_k<<<dim3(1024, 8), 256, 0, stream>>>(h, sf, bfb, hn);
    gemm64_k<M_OUT><<<dim3(128, 8, 1), 256, 36864, stream>>>(
        hn, wout, 8192, 1024, 768, 0, 0, 0,
        outb, nullptr, out);
}

// Round 11
// 4079.028 us; speedup vs baseline: 1.3112x; 1.0808x over previous
//
#include <hip/hip_runtime.h>

typedef __bf16 bf16;
typedef __bf16 bf16x8 __attribute__((ext_vector_type(8)));
typedef __bf16 bf16x4 __attribute__((ext_vector_type(4)));
typedef float  f32x4  __attribute__((ext_vector_type(4)));

#define DEV __device__ __forceinline__

// async global->LDS, 16B per lane; lds dest must be wave-uniform base (HW adds lane*16)
DEV void gload_lds16(const bf16* g, bf16* l) {
    __builtin_amdgcn_global_load_lds(
        (__attribute__((address_space(1))) void*)g,
        (__attribute__((address_space(3))) void*)l, 16, 0, 0);
}

DEV void fence() { asm volatile("" ::: "memory"); }
DEV void bar()   { fence(); __builtin_amdgcn_s_barrier(); fence(); }

// lgkmcnt(0) first so a wave's own ds_reads retire before it can pass the
// barrier and overwrite the buffer (used by the simple 2-barrier kernels).
DEV void barrier_raw() {
    asm volatile("s_waitcnt lgkmcnt(0)" ::: "memory");
    __builtin_amdgcn_s_barrier();
    fence();
}

enum { M_QKV, M_SCORES, M_PV, M_RESID, M_GELU, M_OUT, M_WM };

// ---------------------------------------------------------------------------
// 256x256 8-phase GEMM (m201 template port). 512 thr = 8 waves (2M x 4N),
// BK=64, per-wave 128x64 out, LDS 128KB (2 bufs x {A[256][64] | B[256][64]}).
// Per phase: {ds_read frag-group, stage ONE 128-row half (2 gloads), barrier,
// setprio+16 MFMA, barrier}. vmcnt(4) once per K-tile (2 halves in flight).
// T2 swizzle: stored slot = logical_slot ^ (row&7); inverse-permuted GLOBAL
// source (linear LDS dest, rule #21) + same XOR on ds_read addresses.
// A:[M,K], B:[N,K] bf16 row-major, K % 64 == 0. Grid 1D, %8==0 (XCD swizzle).
// ---------------------------------------------------------------------------
template<int MODE>
__global__ __launch_bounds__(512, 2)
void gemm256_k(const bf16* __restrict__ A, const bf16* __restrict__ B,
               int N, int K, int nbm,
               const float* __restrict__ bias,
               bf16* __restrict__ Cb,
               bf16* __restrict__ qp, bf16* __restrict__ kp, bf16* __restrict__ vp)
{
    extern __shared__ __align__(16) bf16 smem[];   // 65536 elems = 128KB

    const int cpx = gridDim.x >> 3;                // bijective XCD swizzle
    const int wg  = ((int)blockIdx.x & 7) * cpx + ((int)blockIdx.x >> 3);
    const int bm = wg % nbm, bn = wg / nbm;

    const int tid = threadIdx.x, w = tid >> 6, l = tid & 63;
    const int wr = w >> 2, wc = w & 3;
    const int l15 = l & 15, lh = l >> 4;

    const bf16* Ab = A + (long long)bm * 256 * K;
    const bf16* Bb = B + (long long)bn * 256 * K;

    // staging lane constants: thread covers LDS row (.. + w*8 + (l>>3)),
    // stored slot l&7  ->  global slot (l&7) ^ (row&7) = (l&7)^((l>>3)&7)
    const int  lrow = l >> 3;
    const int  lslot = (l & 7) ^ (lrow & 7);
    const long long laneoff = (long long)lrow * K + lslot * 8;

    const int nkt = K >> 6;

    // stage one 128-row half (matsel: 0=A,1=B) of K-tile kt into buf
    auto stage_half = [&](int buf, int kt, int matsel, int half) {
        const bf16* gsrc = (matsel ? Bb : Ab)
                         + (long long)(half * 128 + w * 8) * K + kt * 64 + laneoff;
        bf16* d = smem + buf * 32768 + matsel * 16384 + half * 8192 + w * 512;
        gload_lds16(gsrc,            d);            // rows 0-63 of half
        gload_lds16(gsrc + 64LL * K, d + 4096);     // rows 64-127
    };

    // swizzled fragment reads (row within 256-row region, ks = k-half 0/1)
    auto rdA = [&](const bf16* bp, int mg, int i, int ks) -> bf16x8 {
        const int row = wr * 128 + mg * 64 + i * 16 + l15;
        const int slot = (ks * 4 + lh) ^ (row & 7);
        return *(const bf16x8*)(bp + row * 64 + slot * 8);
    };
    auto rdB = [&](const bf16* bp, int ng, int j, int ks) -> bf16x8 {
        const int row = wc * 64 + ng * 32 + j * 16 + l15;
        const int slot = (ks * 4 + lh) ^ (row & 7);
        return *(const bf16x8*)(bp + 16384 + row * 64 + slot * 8);
    };

    f32x4 acc[8][4];
#pragma unroll
    for (int i = 0; i < 8; ++i)
#pragma unroll
        for (int j = 0; j < 4; ++j) acc[i][j] = (f32x4){0.f, 0.f, 0.f, 0.f};

    // prologue: tile0 all 4 halves -> buf0; tile1 A-halves -> buf1
    stage_half(0, 0, 0, 0); stage_half(0, 0, 0, 1);
    stage_half(0, 0, 1, 0); stage_half(0, 0, 1, 1);
    if (nkt > 1) { stage_half(1, 1, 0, 0); stage_half(1, 1, 0, 1); }
    if (nkt > 1) asm volatile("s_waitcnt vmcnt(4)" ::: "memory");
    else         asm volatile("s_waitcnt vmcnt(0)" ::: "memory");
    bar();

    bf16x8 a[8][2], b[4][2];

    for (int kt = 0; kt < nkt; ++kt) {
        const bf16* bp = smem + (kt & 1) * 32768;
        const int nb = (kt + 1) & 1;

        // ---- phase 0: rd a[mg0] (8) + b[ng0] (4); stage B-lo(t+1); MFMA mg0 x ng0
#pragma unroll
        for (int i = 0; i < 4; ++i) { a[i][0] = rdA(bp, 0, i, 0); a[i][1] = rdA(bp, 0, i, 1); }
#pragma unroll
        for (int j = 0; j < 2; ++j) { b[j][0] = rdB(bp, 0, j, 0); b[j][1] = rdB(bp, 0, j, 1); }
        if (kt + 1 < nkt) stage_half(nb, kt + 1, 1, 0);
        bar();
        __builtin_amdgcn_s_setprio(1);
#pragma unroll
        for (int i = 0; i < 4; ++i)
#pragma unroll
            for (int j = 0; j < 2; ++j)
#pragma unroll
                for (int ks = 0; ks < 2; ++ks)
                    acc[i][j] = __builtin_amdgcn_mfma_f32_16x16x32_bf16(a[i][ks], b[j][ks], acc[i][j], 0, 0, 0);
        __builtin_amdgcn_s_setprio(0);
        bar();

        // ---- phase 1: rd a[mg1] (8); stage B-hi(t+1); MFMA mg1 x ng0
#pragma unroll
        for (int i = 0; i < 4; ++i) { a[4 + i][0] = rdA(bp, 1, i, 0); a[4 + i][1] = rdA(bp, 1, i, 1); }
        if (kt + 1 < nkt) stage_half(nb, kt + 1, 1, 1);
        bar();
        __builtin_amdgcn_s_setprio(1);
#pragma unroll
        for (int i = 0; i < 4; ++i)
#pragma unroll
            for (int j = 0; j < 2; ++j)
#pragma unroll
                for (int ks = 0; ks < 2; ++ks)
                    acc[4 + i][j] = __builtin_amdgcn_mfma_f32_16x16x32_bf16(a[4 + i][ks], b[j][ks], acc[4 + i][j], 0, 0, 0);
        __builtin_amdgcn_s_setprio(0);
        bar();

        // ---- phase 2: rd b[ng1] (4); stage A-lo(t+2); MFMA mg0 x ng1
#pragma unroll
        for (int j = 0; j < 2; ++j) { b[2 + j][0] = rdB(bp, 1, j, 0); b[2 + j][1] = rdB(bp, 1, j, 1); }
        if (kt + 2 < nkt) stage_half(kt & 1, kt + 2, 0, 0);
        bar();
        __builtin_amdgcn_s_setprio(1);
#pragma unroll
        for (int i = 0; i < 4; ++i)
#pragma unroll
            for (int j = 0; j < 2; ++j)
#pragma unroll
                for (int ks = 0; ks < 2; ++ks)
                    acc[i][2 + j] = __builtin_amdgcn_mfma_f32_16x16x32_bf16(a[i][ks], b[2 + j][ks], acc[i][2 + j], 0, 0, 0);
        __builtin_amdgcn_s_setprio(0);
        bar();

        // ---- phase 3: stage A-hi(t+2); MFMA mg1 x ng1; tile-boundary vmcnt
        if (kt + 2 < nkt) stage_half(kt & 1, kt + 2, 0, 1);
        bar();
        __builtin_amdgcn_s_setprio(1);
#pragma unroll
        for (int i = 0; i < 4; ++i)
#pragma unroll
            for (int j = 0; j < 2; ++j)
#pragma unroll
                for (int ks = 0; ks < 2; ++ks)
                    acc[4 + i][2 + j] = __builtin_amdgcn_mfma_f32_16x16x32_bf16(a[4 + i][ks], b[2 + j][ks], acc[4 + i][2 + j], 0, 0, 0);
        __builtin_amdgcn_s_setprio(0);
        if (kt + 1 < nkt) {
            if (kt + 2 < nkt) asm volatile("s_waitcnt vmcnt(4)" ::: "memory");
            else              asm volatile("s_waitcnt vmcnt(0)" ::: "memory");
        }
        bar();
    }

    // epilogue: col = lane&15, row = (lane>>4)*4 + r per frag [m89]
    const int row0 = bm * 256 + wr * 128 + lh * 4;
    const int col0 = bn * 256 + wc * 64 + l15;
#pragma unroll
    for (int i = 0; i < 8; ++i) {
#pragma unroll
        for (int j = 0; j < 4; ++j) {
            const int col = col0 + j * 16;
#pragma unroll
            for (int r = 0; r < 4; ++r) {
                const int row = row0 + i * 16 + r;
                float v = acc[i][j][r];
                if (MODE == M_QKV) {
                    v += bias[col];
                    int hd = col / 192, rr = col % 192;
                    int b2 = row >> 10, s = row & 1023;
                    if (rr < 64)
                        qp[(long long)row * 768 + hd * 64 + rr] = (bf16)(v * 0.03608439182435161f);
                    else if (rr < 128)
                        kp[(long long)row * 768 + hd * 64 + (rr - 64)] = (bf16)v;
                    else
                        vp[((long long)b2 * 768 + hd * 64 + (rr - 128)) * 1024 + s] = (bf16)v;
                } else { // M_GELU
                    float xg = v + bias[col];
                    Cb[(long long)row * N + col] = (bf16)(xg / (1.f + __expf(-1.702f * xg)));
                }
            }
        }
    }
}

// ---------------------------------------------------------------------------
// 128x128 tile GEMM (R7 form): A+B in LDS, 3-buffer 2-ahead counted-vmcnt.
// ---------------------------------------------------------------------------
template<int MODE>
__global__ __launch_bounds__(256)
void gemm_k(const bf16* __restrict__ A, const bf16* __restrict__ B,
            int M, int N, int K,
            long long batchA, long long batchB, long long batchC,
            const float* __restrict__ bias,
            bf16* __restrict__ Cb, float* __restrict__ Cf,
            bf16* __restrict__ qp, bf16* __restrict__ kp, bf16* __restrict__ vp)
{
    const int bm = blockIdx.x, bn = blockIdx.y, bz = blockIdx.z;
    const int kTiles = K >> 5;

    const int tid = threadIdx.x, wid = tid >> 6, lane = tid & 63;
    const bf16* Ab = A + (long long)bz * batchA + (long long)bm * 128 * K;
    const bf16* Bb = B + (long long)bz * batchB + (long long)bn * 128 * K;

    extern __shared__ __align__(16) bf16 smem[];   // 24576 elems = 48KB
    bf16* sA = smem;            // [3][4096]
    bf16* sB = smem + 12288;    // [3][4096]

    const int srow = wid * 16 + (lane >> 2);
    const int scol = (lane & 3) * 8;
    const long long aoff = (long long)srow * K + scol;

    auto stage = [&](int buf, int kt) {
        const bf16* ga = Ab + (long long)kt * 32;
        const bf16* gb = Bb + (long long)kt * 32;
        bf16* a = sA + buf * 4096;
        bf16* b = sB + buf * 4096;
        gload_lds16(ga + aoff,            a + (wid * 16) * 32);
        gload_lds16(ga + aoff + 64LL * K, a + (64 + wid * 16) * 32);
        gload_lds16(gb + aoff,            b + (wid * 16) * 32);
        gload_lds16(gb + aoff + 64LL * K, b + (64 + wid * 16) * 32);
    };

    f32x4 acc[4][4];
#pragma unroll
    for (int m = 0; m < 4; ++m)
#pragma unroll
        for (int n = 0; n < 4; ++n) acc[m][n] = (f32x4){0.f, 0.f, 0.f, 0.f};

    const int npre = kTiles < 2 ? kTiles : 2;
    for (int t = 0; t < npre; ++t) stage(t, t);

    const int wr = wid >> 1, wc = wid & 1;
    const int arow = wr * 64 + (lane & 15);
    const int brow = wc * 64 + (lane & 15);
    const int koff = (lane >> 4) * 8;

    int cur = 0;
    for (int kt = 0; kt < kTiles; ++kt) {
        if (kt + 1 < kTiles) asm volatile("s_waitcnt vmcnt(4)" ::: "memory");
        else                 asm volatile("s_waitcnt vmcnt(0)" ::: "memory");
        barrier_raw();
        if (kt + 2 < kTiles) {
            int ib = cur - 1; if (ib < 0) ib = 2;   // (cur+2)%3
            stage(ib, kt + 2);
        }

        const bf16* a = sA + cur * 4096;
        const bf16* b = sB + cur * 4096;
        bf16x8 af[4], bfr[4];
#pragma unroll
        for (int m = 0; m < 4; ++m)
            af[m] = *(const bf16x8*)&a[(arow + m * 16) * 32 + koff];
#pragma unroll
        for (int n = 0; n < 4; ++n)
            bfr[n] = *(const bf16x8*)&b[(brow + n * 16) * 32 + koff];
#pragma unroll
        for (int m = 0; m < 4; ++m)
#pragma unroll
            for (int n = 0; n < 4; ++n)
                acc[m][n] = __builtin_amdgcn_mfma_f32_16x16x32_bf16(af[m], bfr[n], acc[m][n], 0, 0, 0);

        cur = (cur == 2) ? 0 : cur + 1;
    }

    const int cr0 = bm * 128 + wr * 64 + (lane >> 4) * 4;
    const int cc0 = bn * 128 + wc * 64 + (lane & 15);
#pragma unroll
    for (int m = 0; m < 4; ++m) {
#pragma unroll
        for (int n = 0; n < 4; ++n) {
            const int col = cc0 + n * 16;
#pragma unroll
            for (int r = 0; r < 4; ++r) {
                const int row = cr0 + m * 16 + r;
                float v = acc[m][n][r];
                if (MODE == M_GELU) {
                    float xg = v + bias[col];
                    Cb[(long long)row * N + col] = (bf16)(xg / (1.f + __expf(-1.702f * xg)));
                } else if (MODE == M_RESID) {
                    long long idx = (long long)row * N + col;
                    Cf[idx] += v + bias[col];
                } else if (MODE == M_WM) {
                    Cb[(long long)bz * batchC + (long long)row * N + col] = (bf16)v;
                } else { // M_OUT (fp32 + bias)
                    Cf[(long long)row * N + col] = v + bias[col];
                }
            }
        }
    }
}

// ---------------------------------------------------------------------------
// 64x128 tile GEMM (R7 form), 3-buffer 2-ahead, shared LDS 36KB -> 4/CU.
// For scores/PV (causal granularity), mlp2, o-merged, final out.
// ---------------------------------------------------------------------------
template<int MODE>
__global__ __launch_bounds__(256)
void gemm64_k(const bf16* __restrict__ A, const bf16* __restrict__ B,
              int M, int N, int K,
              long long batchA, long long batchB, long long batchC,
              const float* __restrict__ bias,
              bf16* __restrict__ Cb, float* __restrict__ Cf)
{
    const int bm = blockIdx.x, bn = blockIdx.y, bz = blockIdx.z;
    if (MODE == M_SCORES && 2 * bn > bm) return;     // fully-masked tile
    int kTiles = K >> 5;
    if (MODE == M_PV) {                              // P[:,k]==0 for k>row
        int lim = 2 * bm + 2;
        if (lim < kTiles) kTiles = lim;
    }

    const int tid = threadIdx.x, wid = tid >> 6, lane = tid & 63;
    const bf16* Ab = A + (long long)bz * batchA + (long long)bm * 64 * K;
    const bf16* Bb = B + (long long)bz * batchB + (long long)bn * 128 * K;

    extern __shared__ __align__(16) bf16 smem[];   // 18432 elems = 36KB
    bf16* sA = smem;            // [3][2048]
    bf16* sB = smem + 6144;     // [3][4096]

    const int srow = wid * 16 + (lane >> 2);          // 0..63
    const int scol = (lane & 3) * 8;
    const long long aoff = (long long)srow * K + scol;

    auto stage = [&](int buf, int kt) {
        const bf16* ga = Ab + (long long)kt * 32;
        const bf16* gb = Bb + (long long)kt * 32;
        gload_lds16(ga + aoff,            sA + buf * 2048 + (wid * 16) * 32);
        gload_lds16(gb + aoff,            sB + buf * 4096 + (wid * 16) * 32);
        gload_lds16(gb + aoff + 64LL * K, sB + buf * 4096 + (64 + wid * 16) * 32);
    };

    f32x4 acc[2][4];
#pragma unroll
    for (int m = 0; m < 2; ++m)
#pragma unroll
        for (int n = 0; n < 4; ++n) acc[m][n] = (f32x4){0.f, 0.f, 0.f, 0.f};

    const int npre = kTiles < 2 ? kTiles : 2;
    for (int t = 0; t < npre; ++t) stage(t, t);

    const int wr = wid >> 1, wc = wid & 1;
    const int arow = wr * 32 + (lane & 15);
    const int brow = wc * 64 + (lane & 15);
    const int koff = (lane >> 4) * 8;

    int cur = 0;
    for (int kt = 0; kt < kTiles; ++kt) {
        if (kt + 1 < kTiles) asm volatile("s_waitcnt vmcnt(3)" ::: "memory");
        else                 asm volatile("s_waitcnt vmcnt(0)" ::: "memory");
        barrier_raw();
        if (kt + 2 < kTiles) {
            int ib = cur - 1; if (ib < 0) ib = 2;   // (cur+2)%3
            stage(ib, kt + 2);
        }

        const bf16* a = sA + cur * 2048;
        const bf16* b = sB + cur * 4096;
        bf16x8 af[2], bfr[4];
#pragma unroll
        for (int m = 0; m < 2; ++m)
            af[m] = *(const bf16x8*)&a[(arow + m * 16) * 32 + koff];
#pragma unroll
        for (int n = 0; n < 4; ++n)
            bfr[n] = *(const bf16x8*)&b[(brow + n * 16) * 32 + koff];
#pragma unroll
        for (int m = 0; m < 2; ++m)
#pragma unroll
            for (int n = 0; n < 4; ++n)
                acc[m][n] = __builtin_amdgcn_mfma_f32_16x16x32_bf16(af[m], bfr[n], acc[m][n], 0, 0, 0);

        cur = (cur == 2) ? 0 : cur + 1;
    }

    const int cr0 = bm * 64 + wr * 32 + (lane >> 4) * 4;
    const int cc0 = bn * 128 + wc * 64 + (lane & 15);
#pragma unroll
    for (int m = 0; m < 2; ++m) {
#pragma unroll
        for (int n = 0; n < 4; ++n) {
            const int col = cc0 + n * 16;
#pragma unroll
            for (int r = 0; r < 4; ++r) {
                const int row = cr0 + m * 16 + r;
                float v = acc[m][n][r];
                if (MODE == M_SCORES || MODE == M_PV) {
                    Cb[(long long)bz * batchC + (long long)row * N + col] = (bf16)v;
                } else if (MODE == M_RESID) {
                    long long idx = (long long)row * N + col;
                    Cf[idx] += v + bias[col];
                } else { // M_OUT (fp32 + bias)
                    Cf[(long long)row * N + col] = v + bias[col];
                }
            }
        }
    }
}

// ---------------------------------------------------------------------------
__global__ __launch_bounds__(256)
void cvt_bf16_k(const float* __restrict__ in, bf16* __restrict__ out, int n4)
{
    int i = blockIdx.x * 256 + threadIdx.x;
    if (i >= n4) return;
    float4 f = ((const float4*)in)[i];
    bf16x4 o = { (bf16)f.x, (bf16)f.y, (bf16)f.z, (bf16)f.w };
    ((bf16x4*)out)[i] = o;
}

// out[l][c][r] = (bf16) in[l][r][c]   (n x n per layer, n mult of 32)
__global__ __launch_bounds__(256)
void transpose_cvt_k(const float* __restrict__ in, bf16* __restrict__ out, int n)
{
    __shared__ float t[32][33];
    const int l = blockIdx.z;
    const int r0 = blockIdx.y * 32, c0 = blockIdx.x * 32;
    const float* src = in + (long long)l * n * n;
    bf16* dst = out + (long long)l * n * n;
    const int tx = threadIdx.x & 31, ty = threadIdx.x >> 5;   // 32x8
#pragma unroll
    for (int i = 0; i < 32; i += 8)
        t[ty + i][tx] = src[(long long)(r0 + ty + i) * n + c0 + tx];
    __syncthreads();
#pragma unroll
    for (int i = 0; i < 32; i += 8)
        dst[(long long)(c0 + ty + i) * n + r0 + tx] = (bf16)t[tx][ty + i];
}

// merged bias: bm[l][a] = sum_j o2w[l][a][j]*o1b[l][j] + o2b[l][a]; one wave per (l,a)
__global__ __launch_bounds__(256)
void bias_merge_k(const float* __restrict__ o2w, const float* __restrict__ o1b,
                  const float* __restrict__ o2b, float* __restrict__ bm, int total)
{
    const int wid = threadIdx.x >> 6, lane = threadIdx.x & 63;
    const int idx = blockIdx.x * 4 + wid;
    if (idx >= total) return;
    const int l = idx / 768, a = idx - l * 768;
    const float* wrow = o2w + ((long long)l * 768 + a) * 768;
    const float* brow = o1b + (long long)l * 768;
    float s = 0.f;
#pragma unroll
    for (int j = 0; j < 12; ++j) {
        int c = j * 64 + lane;
        s += wrow[c] * brow[c];
    }
#pragma unroll
    for (int o = 32; o; o >>= 1) s += __shfl_down(s, o);
    if (lane == 0) bm[idx] = s + o2b[(long long)l * 768 + a];
}

__global__ __launch_bounds__(256)
void cond_proj_k(const float* __restrict__ label, const float* __restrict__ sw,
                 const float* __restrict__ bw, float* __restrict__ scale,
                 float* __restrict__ bias, int total)
{
    int idx = blockIdx.x * 256 + threadIdx.x;
    if (idx >= total) return;
    int l = idx / 6144;
    int rem = idx - l * 6144;
    int b = rem / 768, d = rem - (rem / 768) * 768;
    const float* lab = label + b * 17;
    const float* swp = sw + ((long long)l * 768 + d) * 17;
    const float* bwp = bw + ((long long)l * 768 + d) * 17;
    float s = 0.f, bb = 0.f;
#pragma unroll
    for (int c = 0; c < 17; ++c) { float lv = lab[c]; s += lv * swp[c]; bb += lv * bwp[c]; }
    scale[idx] = s;
    bias[idx]  = bb;
}

// h[b,s,:] = (s==0 ? sos : xe[b,s-1,:]) + pos_bias(s)
__global__ __launch_bounds__(256)
void shift_pos_k(const float* __restrict__ xe, const float* __restrict__ sos,
                 const float* __restrict__ p0, const float* __restrict__ p1,
                 const float* __restrict__ p2, float* __restrict__ h)
{
    const int s = blockIdx.x, b = blockIdx.y;
    const int i0 = s >> 8, i1 = (s >> 4) & 15, i2 = s & 15;
    const float* xr = xe + ((long long)b * 1024 + (s - 1)) * 768;
#pragma unroll
    for (int j = 0; j < 3; ++j) {
        const int d = j * 256 + threadIdx.x;
        float v = (s == 0) ? sos[d] : xr[d];
        float pbv = (d < 256) ? p0[i0 * 256 + d]
                  : (d < 512) ? p1[i1 * 256 + (d - 256)]
                              : p2[i2 * 256 + (d - 512)];
        h[((long long)b * 1024 + s) * 768 + d] = v + pbv;
    }
}

__global__ __launch_bounds__(256)
void cond_ln_k(const float* __restrict__ h, const float* __restrict__ scale,
               const float* __restrict__ bias, bf16* __restrict__ out)
{
    const long long row = (long long)blockIdx.y * 1024 + blockIdx.x;
    const int b = blockIdx.y;
    const float* hr = h + row * 768;
    float v[3], sum = 0.f, sq = 0.f;
#pragma unroll
    for (int j = 0; j < 3; ++j) {
        v[j] = hr[j * 256 + threadIdx.x];
        sum += v[j]; sq += v[j] * v[j];
    }
    __shared__ float sm[8];
#pragma unroll
    for (int o = 32; o; o >>= 1) { sum += __shfl_down(sum, o); sq += __shfl_down(sq, o); }
    const int wid = threadIdx.x >> 6;
    if ((threadIdx.x & 63) == 0) { sm[wid] = sum; sm[4 + wid] = sq; }
    __syncthreads();
    sum = sm[0] + sm[1] + sm[2] + sm[3];
    sq  = sm[4] + sm[5] + sm[6] + sm[7];
    const float mean = sum * (1.f / 768.f);
    const float var  = sq * (1.f / 768.f) - mean * mean;
    const float rs   = rsqrtf(var + 1e-6f);
    const float* sc = scale + (long long)b * 768;
    const float* bi = bias  + (long long)b * 768;
    bf16* orow = out + row * 768;
#pragma unroll
    for (int j = 0; j < 3; ++j) {
        const int d = j * 256 + threadIdx.x;
        orow[d] = (bf16)((v[j] - mean) * rs * (1.f + sc[d]) + bi[d]);
    }
}

// causal softmax over row i. Touches only cols < ceil64(i+1).
__global__ __launch_bounds__(256)
void softmax_k(bf16* __restrict__ P)
{
    const int i = blockIdx.x, b = blockIdx.y;
    bf16* row = P + ((long long)b * 1024 + i) * 1024;
    const int len = i + 1;
    const int lim = (i | 63) + 1;
    float v[4], mx = -1e30f;
#pragma unroll
    for (int j = 0; j < 4; ++j) {
        int c = j * 256 + threadIdx.x;
        v[j] = (c < len) ? (float)row[c] : -1e30f;
        mx = fmaxf(mx, v[j]);
    }
    __shared__ float sm[8];
#pragma unroll
    for (int o = 32; o; o >>= 1) mx = fmaxf(mx, __shfl_down(mx, o));
    const int wid = threadIdx.x >> 6;
    if ((threadIdx.x & 63) == 0) sm[wid] = mx;
    __syncthreads();
    mx = fmaxf(fmaxf(sm[0], sm[1]), fmaxf(sm[2], sm[3]));
    float s = 0.f;
#pragma unroll
    for (int j = 0; j < 4; ++j) {
        v[j] = __expf(v[j] - mx);
        s += ((j * 256 + threadIdx.x) < len) ? v[j] : 0.f;
    }
#pragma unroll
    for (int o = 32; o; o >>= 1) s += __shfl_down(s, o);
    if ((threadIdx.x & 63) == 0) sm[4 + wid] = s;
    __syncthreads();
    s = sm[4] + sm[5] + sm[6] + sm[7];
    const float inv = 1.f / s;
#pragma unroll
    for (int j = 0; j < 4; ++j) {
        int c = j * 256 + threadIdx.x;
        if (c < lim) row[c] = (c < len) ? (bf16)(v[j] * inv) : (bf16)0.f;
    }
}

__global__ __launch_bounds__(256)
void fill_k(float* o, int n, float v)
{
    int i = blockIdx.x * 256 + threadIdx.x;
    if (i < n) o[i] = v;
}

// ---------------------------------------------------------------------------
extern "C" void kernel_launch(void* const* d_in, const int* in_sizes, int n_in,
                              void* d_out, int out_size, void* d_ws, size_t ws_size,
                              hipStream_t stream)
{
    (void)in_sizes; (void)n_in;
    const float* x     = (const float*)d_in[0];
    const float* label = (const float*)d_in[2];
    const float* dw    = (const float*)d_in[3];
    const float* db    = (const float*)d_in[4];
    const float* sos   = (const float*)d_in[5];
    const float* p0    = (const float*)d_in[6];
    const float* p1    = (const float*)d_in[7];
    const float* p2    = (const float*)d_in[8];
    const float* ln1sw = (const float*)d_in[9];
    const float* ln1bw = (const float*)d_in[10];
    const float* qkvw  = (const float*)d_in[11];
    const float* qkvb  = (const float*)d_in[12];
    const float* ao1w  = (const float*)d_in[13];
    const float* ao1b  = (const float*)d_in[14];
    const float* ao2w  = (const float*)d_in[15];
    const float* ao2b  = (const float*)d_in[16];
    const float* ln2sw = (const float*)d_in[17];
    const float* ln2bw = (const float*)d_in[18];
    const float* m1w   = (const float*)d_in[19];
    const float* m1b   = (const float*)d_in[20];
    const float* m2w   = (const float*)d_in[21];
    const float* m2b   = (const float*)d_in[22];
    const float* lnfsw = (const float*)d_in[23];
    const float* lnfbw = (const float*)d_in[24];
    const float* outw  = (const float*)d_in[25];
    const float* outb  = (const float*)d_in[26];
    float* out = (float*)d_out;

    char* p = (char*)d_ws;
    auto alloc = [&](size_t bytes) { void* r = (void*)p; p += (bytes + 255) & ~(size_t)255; return r; };
    float* h    = (float*)alloc(8192LL * 768 * 4);
    bf16*  hn   = (bf16*) alloc(8192LL * 768 * 2);
    bf16*  q    = (bf16*) alloc(8192LL * 768 * 2);
    bf16*  kbuf = (bf16*) alloc(8192LL * 768 * 2);
    bf16*  vT   = (bf16*) alloc(8192LL * 768 * 2);   // [B,768,1024]
    bf16*  P    = (bf16*) alloc(8LL * 1024 * 1024 * 2);
    bf16*  attn = (bf16*) alloc(8192LL * 768 * 2);
    bf16*  mb   = (bf16*) alloc(8192LL * 3072 * 2);
    bf16*  wout = (bf16*) alloc(1024LL * 768 * 2);
    bf16*  wmA  = (bf16*) alloc(12LL * 768 * 768 * 2);   // merged o2@o1, bf16
    float* bmA  = (float*)alloc(12LL * 768 * 4);         // merged o-bias
    float* s1   = (float*)alloc(12LL * 8 * 768 * 4);
    float* b1   = (float*)alloc(12LL * 8 * 768 * 4);
    float* s2   = (float*)alloc(12LL * 8 * 768 * 4);
    float* b2   = (float*)alloc(12LL * 8 * 768 * 4);
    float* sf   = (float*)alloc(8LL * 768 * 4);
    float* bfb  = (float*)alloc(8LL * 768 * 4);

    size_t base_needed = (size_t)(p - (char*)d_ws);
    if (base_needed + 16LL * 1024 * 1024 > ws_size) {
        fill_k<<<(out_size + 255) / 256, 256, 0, stream>>>(out, out_size, 1e9f);
        return;
    }

    const long long SZ_QKV = 2304LL * 768, SZ_O = 768LL * 768, SZ_M = 3072LL * 768;
    size_t all_bytes = (size_t)(12 * (SZ_QKV + 2 * SZ_M)) * 2;
    bool allw = ((size_t)(p - (char*)d_ws) + all_bytes + 4096 <= ws_size);

    bf16 *wqkvA, *wm1A, *wm2A;
    if (allw) {
        wqkvA = (bf16*)alloc(12 * SZ_QKV * 2);
        wm1A  = (bf16*)alloc(12 * SZ_M * 2);
        wm2A  = (bf16*)alloc(12 * SZ_M * 2);
    } else {
        wqkvA = (bf16*)alloc(SZ_QKV * 2);
        wm1A  = (bf16*)alloc(SZ_M * 2);
        wm2A  = (bf16*)alloc(SZ_M * 2);
    }

    // one-time scratch aliased onto regions unused until the layer loop:
    bf16*  xbf   = (bf16*)P;
    bf16*  dwbf  = (bf16*)P + 524288;
    bf16*  wo2bf = (bf16*)P + 1048576;
    float* xe    = (float*)mb;
    bf16*  o1t   = mb + 12582912;

    // --- one-time precompute ---
    cvt_bf16_k<<<1024 * 768 / 4 / 256, 256, 0, stream>>>(outw, wout, 1024 * 768 / 4);
    cond_proj_k<<<(12 * 8 * 768 + 255) / 256, 256, 0, stream>>>(label, ln1sw, ln1bw, s1, b1, 12 * 8 * 768);
    cond_proj_k<<<(12 * 8 * 768 + 255) / 256, 256, 0, stream>>>(label, ln2sw, ln2bw, s2, b2, 12 * 8 * 768);
    cond_proj_k<<<(8 * 768 + 255) / 256, 256, 0, stream>>>(label, lnfsw, lnfbw, sf, bfb, 8 * 768);

    if (allw) {
        cvt_bf16_k<<<(int)(12 * SZ_QKV / 4 / 256), 256, 0, stream>>>(qkvw, wqkvA, (int)(12 * SZ_QKV / 4));
        cvt_bf16_k<<<(int)(12 * SZ_M / 4 / 256),   256, 0, stream>>>(m1w,  wm1A,  (int)(12 * SZ_M / 4));
        cvt_bf16_k<<<(int)(12 * SZ_M / 4 / 256),   256, 0, stream>>>(m2w,  wm2A,  (int)(12 * SZ_M / 4));
    }

    // merged out-proj: Wm[l] = o2[l] @ o1[l]  (bf16), bm[l] = o2[l]@o1b[l] + o2b[l]
    cvt_bf16_k<<<(int)(12 * SZ_O / 4 / 256), 256, 0, stream>>>(ao2w, wo2bf, (int)(12 * SZ_O / 4));
    transpose_cvt_k<<<dim3(24, 24, 12), 256, 0, stream>>>(ao1w, o1t, 768);
    gemm_k<M_WM><<<dim3(6, 6, 12), 256, 49152, stream>>>(
        wo2bf, o1t, 768, 768, 768, SZ_O, SZ_O, SZ_O,
        nullptr, wmA, nullptr, nullptr, nullptr, nullptr);
    bias_merge_k<<<(12 * 768 + 3) / 4, 256, 0, stream>>>(ao2w, ao1b, ao2b, bmA, 12 * 768);

    // embed: x->bf16, xe = x @ dw^T + db (fp32), then shift+pos
    cvt_bf16_k<<<8192 * 64 / 4 / 256, 256, 0, stream>>>(x, xbf, 8192 * 64 / 4);
    cvt_bf16_k<<<768 * 64 / 4 / 256, 256, 0, stream>>>(dw, dwbf, 768 * 64 / 4);
    gemm_k<M_OUT><<<dim3(64, 6, 1), 256, 49152, stream>>>(
        xbf, dwbf, 8192, 768, 64, 0, 0, 0, db, nullptr, xe, nullptr, nullptr, nullptr);
    shift_pos_k<<<dim3(1024, 8), 256, 0, stream>>>(xe, sos, p0, p1, p2, h);

    for (int l = 0; l < 12; ++l) {
        bf16 *wqkv, *wm1, *wm2;
        if (allw) {
            wqkv = wqkvA + (long long)l * SZ_QKV;
            wm1  = wm1A  + (long long)l * SZ_M;
            wm2  = wm2A  + (long long)l * SZ_M;
        } else {
            wqkv = wqkvA; wm1 = wm1A; wm2 = wm2A;
            cvt_bf16_k<<<(int)(SZ_QKV / 4 / 256), 256, 0, stream>>>(qkvw + (long long)l * SZ_QKV, wqkv, (int)(SZ_QKV / 4));
            cvt_bf16_k<<<(int)(SZ_M / 4 / 256),   256, 0, stream>>>(m1w  + (long long)l * SZ_M,   wm1,  (int)(SZ_M / 4));
            cvt_bf16_k<<<(int)(SZ_M / 4 / 256),   256, 0, stream>>>(m2w  + (long long)l * SZ_M,   wm2,  (int)(SZ_M / 4));
        }

        cond_ln_k<<<dim3(1024, 8), 256, 0, stream>>>(h, s1 + (long long)l * 6144, b1 + (long long)l * 6144, hn);

        // qkv: 256^2 8-phase, grid 32*9 = 288 (%8==0)
        gemm256_k<M_QKV><<<288, 512, 131072, stream>>>(
            hn, wqkv, 2304, 768, 32,
            qkvb + (long long)l * 2304, nullptr, q, kbuf, vT);

        gemm64_k<M_SCORES><<<dim3(16, 8, 8), 256, 36864, stream>>>(
            q, kbuf, 1024, 1024, 768, 1024LL * 768, 1024LL * 768, 1024LL * 1024,
            nullptr, P, nullptr);

        softmax_k<<<dim3(1024, 8), 256, 0, stream>>>(P);

        gemm64_k<M_PV><<<dim3(16, 6, 8), 256, 36864, stream>>>(
            P, vT, 1024, 768, 1024, 1024LL * 1024, 768LL * 1024, 1024LL * 768,
            nullptr, attn, nullptr);

        gemm64_k<M_RESID><<<dim3(128, 6, 1), 256, 36864, stream>>>(
            attn, wmA + (long long)l * SZ_O, 8192, 768, 768, 0, 0, 0,
            bmA + (long long)l * 768, nullptr, h);

        cond_ln_k<<<dim3(1024, 8), 256, 0, stream>>>(h, s2 + (long long)l * 6144, b2 + (long long)l * 6144, hn);

        // mlp1: 256^2 8-phase, grid 32*12 = 384 (%8==0)
        gemm256_k<M_GELU><<<384, 512, 131072, stream>>>(
            hn, wm1, 3072, 768, 32,
            m1b + (long long)l * 3072, mb, nullptr, nullptr, nullptr);

        gemm64_k<M_RESID><<<dim3(128, 6, 1), 256, 36864, stream>>>(
            mb, wm2, 8192, 768, 3072, 0, 0, 0,
            m2b + (long long)l * 768, nullptr, h);
    }

    cond_ln_k<<<dim3(1024, 8), 256, 0, stream>>>(h, sf, bfb, hn);
    gemm64_k<M_OUT><<<dim3(128, 8, 1), 256, 36864, stream>>>(
        hn, wout, 8192, 1024, 768, 0, 0, 0,
        outb, nullptr, out);
}

// Round 12
// 3893.991 us; speedup vs baseline: 1.3735x; 1.0475x over previous
//
#include <hip/hip_runtime.h>

typedef __bf16 bf16;
typedef __bf16 bf16x8 __attribute__((ext_vector_type(8)));
typedef __bf16 bf16x4 __attribute__((ext_vector_type(4)));
typedef float  f32x4  __attribute__((ext_vector_type(4)));

#define DEV __device__ __forceinline__

// async global->LDS, 16B per lane; lds dest must be wave-uniform base (HW adds lane*16)
DEV void gload_lds16(const bf16* g, bf16* l) {
    __builtin_amdgcn_global_load_lds(
        (__attribute__((address_space(1))) void*)g,
        (__attribute__((address_space(3))) void*)l, 16, 0, 0);
}

// lgkmcnt(0) first: wave's own ds_reads complete before the barrier, so the
// next buffer-overwrite (gload_lds) can never race an in-flight read.
DEV void barrier_raw() {
    asm volatile("s_waitcnt lgkmcnt(0)" ::: "memory");
    __builtin_amdgcn_s_barrier();
    asm volatile("" ::: "memory");
}

enum { M_QKV, M_SCORES, M_PV, M_RESID, M_GELU, M_OUT, M_WM };

// ---------------------------------------------------------------------------
// 128x128 tile GEMM (R7 form): A+B in LDS, 3-buffer 2-ahead counted-vmcnt.
// C[m,n] = sum_k A[m,k]*B[n,k]; A:[M,K], B:[N,K] bf16 row-major. LDS 48KB.
// ---------------------------------------------------------------------------
template<int MODE>
__global__ __launch_bounds__(256)
void gemm_k(const bf16* __restrict__ A, const bf16* __restrict__ B,
            int M, int N, int K,
            long long batchA, long long batchB, long long batchC,
            const float* __restrict__ bias,
            bf16* __restrict__ Cb, float* __restrict__ Cf,
            bf16* __restrict__ qp, bf16* __restrict__ kp, bf16* __restrict__ vp)
{
    const int bm = blockIdx.x, bn = blockIdx.y, bz = blockIdx.z;
    const int kTiles = K >> 5;

    const int tid = threadIdx.x, wid = tid >> 6, lane = tid & 63;
    const bf16* Ab = A + (long long)bz * batchA + (long long)bm * 128 * K;
    const bf16* Bb = B + (long long)bz * batchB + (long long)bn * 128 * K;

    extern __shared__ __align__(16) bf16 smem[];   // 24576 elems = 48KB
    bf16* sA = smem;            // [3][4096]
    bf16* sB = smem + 12288;    // [3][4096]

    const int srow = wid * 16 + (lane >> 2);
    const int scol = (lane & 3) * 8;
    const long long aoff = (long long)srow * K + scol;

    auto stage = [&](int buf, int kt) {
        const bf16* ga = Ab + (long long)kt * 32;
        const bf16* gb = Bb + (long long)kt * 32;
        bf16* a = sA + buf * 4096;
        bf16* b = sB + buf * 4096;
        gload_lds16(ga + aoff,            a + (wid * 16) * 32);
        gload_lds16(ga + aoff + 64LL * K, a + (64 + wid * 16) * 32);
        gload_lds16(gb + aoff,            b + (wid * 16) * 32);
        gload_lds16(gb + aoff + 64LL * K, b + (64 + wid * 16) * 32);
    };

    f32x4 acc[4][4];
#pragma unroll
    for (int m = 0; m < 4; ++m)
#pragma unroll
        for (int n = 0; n < 4; ++n) acc[m][n] = (f32x4){0.f, 0.f, 0.f, 0.f};

    const int npre = kTiles < 2 ? kTiles : 2;
    for (int t = 0; t < npre; ++t) stage(t, t);

    const int wr = wid >> 1, wc = wid & 1;
    const int arow = wr * 64 + (lane & 15);
    const int brow = wc * 64 + (lane & 15);
    const int koff = (lane >> 4) * 8;

    int cur = 0;
    for (int kt = 0; kt < kTiles; ++kt) {
        if (kt + 1 < kTiles) asm volatile("s_waitcnt vmcnt(4)" ::: "memory");
        else                 asm volatile("s_waitcnt vmcnt(0)" ::: "memory");
        barrier_raw();   // all waves: stage(kt) visible; iter kt-1 reads done
        if (kt + 2 < kTiles) {
            int ib = cur - 1; if (ib < 0) ib = 2;   // (cur+2)%3
            stage(ib, kt + 2);
        }

        const bf16* a = sA + cur * 4096;
        const bf16* b = sB + cur * 4096;
        bf16x8 af[4], bfr[4];
#pragma unroll
        for (int m = 0; m < 4; ++m)
            af[m] = *(const bf16x8*)&a[(arow + m * 16) * 32 + koff];
#pragma unroll
        for (int n = 0; n < 4; ++n)
            bfr[n] = *(const bf16x8*)&b[(brow + n * 16) * 32 + koff];
#pragma unroll
        for (int m = 0; m < 4; ++m)
#pragma unroll
            for (int n = 0; n < 4; ++n)
                acc[m][n] = __builtin_amdgcn_mfma_f32_16x16x32_bf16(af[m], bfr[n], acc[m][n], 0, 0, 0);

        cur = (cur == 2) ? 0 : cur + 1;
    }

    // C/D layout: col = lane&15, row = (lane>>4)*4 + r   [learn_hip m89]
    const int cr0 = bm * 128 + wr * 64 + (lane >> 4) * 4;
    const int cc0 = bn * 128 + wc * 64 + (lane & 15);
#pragma unroll
    for (int m = 0; m < 4; ++m) {
#pragma unroll
        for (int n = 0; n < 4; ++n) {
            const int col = cc0 + n * 16;
#pragma unroll
            for (int r = 0; r < 4; ++r) {
                const int row = cr0 + m * 16 + r;
                float v = acc[m][n][r];
                if (MODE == M_QKV) {
                    v += bias[col];
                    int hd = col / 192, rr = col % 192;
                    int b2 = row >> 10, s = row & 1023;
                    if (rr < 64)
                        qp[(long long)row * 768 + hd * 64 + rr] = (bf16)(v * 0.03608439182435161f);
                    else if (rr < 128)
                        kp[(long long)row * 768 + hd * 64 + (rr - 64)] = (bf16)v;
                    else
                        vp[((long long)b2 * 768 + hd * 64 + (rr - 128)) * 1024 + s] = (bf16)v;
                } else if (MODE == M_GELU) {
                    float xg = v + bias[col];
                    Cb[(long long)row * N + col] = (bf16)(xg / (1.f + __expf(-1.702f * xg)));
                } else if (MODE == M_RESID) {
                    long long idx = (long long)row * N + col;
                    Cf[idx] += v + bias[col];
                } else if (MODE == M_WM) {
                    Cb[(long long)bz * batchC + (long long)row * N + col] = (bf16)v;
                } else { // M_OUT (fp32 + bias)
                    Cf[(long long)row * N + col] = v + bias[col];
                }
            }
        }
    }
}

// ---------------------------------------------------------------------------
// 64x128 tile GEMM — 4-buffer 3-ahead counted-vmcnt (depth 3 AND 3 blocks/CU:
// the untried cell; R6 had depth-3 at 2/CU, R7 residency at depth-2, both 88).
// LDS 48KB = 4 x (A 4KB + B 8KB). For scores/PV (causal), mlp2, o-merged, out.
// ---------------------------------------------------------------------------
template<int MODE>
__global__ __launch_bounds__(256)
void gemm64_k(const bf16* __restrict__ A, const bf16* __restrict__ B,
              int M, int N, int K,
              long long batchA, long long batchB, long long batchC,
              const float* __restrict__ bias,
              bf16* __restrict__ Cb, float* __restrict__ Cf)
{
    const int bm = blockIdx.x, bn = blockIdx.y, bz = blockIdx.z;
    if (MODE == M_SCORES && 2 * bn > bm) return;     // fully-masked tile
    int kTiles = K >> 5;
    if (MODE == M_PV) {                              // P[:,k]==0 for k>row
        int lim = 2 * bm + 2;
        if (lim < kTiles) kTiles = lim;
    }

    const int tid = threadIdx.x, wid = tid >> 6, lane = tid & 63;
    const bf16* Ab = A + (long long)bz * batchA + (long long)bm * 64 * K;
    const bf16* Bb = B + (long long)bz * batchB + (long long)bn * 128 * K;

    extern __shared__ __align__(16) bf16 smem[];   // 24576 elems = 48KB
    bf16* sA = smem;            // [4][2048]
    bf16* sB = smem + 8192;     // [4][4096]

    const int srow = wid * 16 + (lane >> 2);          // 0..63
    const int scol = (lane & 3) * 8;
    const long long aoff = (long long)srow * K + scol;

    auto stage = [&](int buf, int kt) {
        const bf16* ga = Ab + (long long)kt * 32;
        const bf16* gb = Bb + (long long)kt * 32;
        gload_lds16(ga + aoff,            sA + buf * 2048 + (wid * 16) * 32);
        gload_lds16(gb + aoff,            sB + buf * 4096 + (wid * 16) * 32);
        gload_lds16(gb + aoff + 64LL * K, sB + buf * 4096 + (64 + wid * 16) * 32);
    };

    f32x4 acc[2][4];
#pragma unroll
    for (int m = 0; m < 2; ++m)
#pragma unroll
        for (int n = 0; n < 4; ++n) acc[m][n] = (f32x4){0.f, 0.f, 0.f, 0.f};

    const int npre = kTiles < 3 ? kTiles : 3;
    for (int t = 0; t < npre; ++t) stage(t, t);

    const int wr = wid >> 1, wc = wid & 1;
    const int arow = wr * 32 + (lane & 15);
    const int brow = wc * 64 + (lane & 15);
    const int koff = (lane >> 4) * 8;

    for (int kt = 0; kt < kTiles; ++kt) {
        const int rem = kTiles - 1 - kt;
        if (rem >= 2)      asm volatile("s_waitcnt vmcnt(6)" ::: "memory");
        else if (rem == 1) asm volatile("s_waitcnt vmcnt(3)" ::: "memory");
        else               asm volatile("s_waitcnt vmcnt(0)" ::: "memory");
        barrier_raw();   // stage(kt) visible; iter kt-1 reads retired everywhere
        if (kt + 3 < kTiles) stage((kt + 3) & 3, kt + 3);

        const int cur = kt & 3;
        const bf16* a = sA + cur * 2048;
        const bf16* b = sB + cur * 4096;
        bf16x8 af[2], bfr[4];
#pragma unroll
        for (int m = 0; m < 2; ++m)
            af[m] = *(const bf16x8*)&a[(arow + m * 16) * 32 + koff];
#pragma unroll
        for (int n = 0; n < 4; ++n)
            bfr[n] = *(const bf16x8*)&b[(brow + n * 16) * 32 + koff];
#pragma unroll
        for (int m = 0; m < 2; ++m)
#pragma unroll
            for (int n = 0; n < 4; ++n)
                acc[m][n] = __builtin_amdgcn_mfma_f32_16x16x32_bf16(af[m], bfr[n], acc[m][n], 0, 0, 0);
    }

    const int cr0 = bm * 64 + wr * 32 + (lane >> 4) * 4;
    const int cc0 = bn * 128 + wc * 64 + (lane & 15);
#pragma unroll
    for (int m = 0; m < 2; ++m) {
#pragma unroll
        for (int n = 0; n < 4; ++n) {
            const int col = cc0 + n * 16;
#pragma unroll
            for (int r = 0; r < 4; ++r) {
                const int row = cr0 + m * 16 + r;
                float v = acc[m][n][r];
                if (MODE == M_SCORES || MODE == M_PV) {
                    Cb[(long long)bz * batchC + (long long)row * N + col] = (bf16)v;
                } else if (MODE == M_RESID) {
                    long long idx = (long long)row * N + col;
                    Cf[idx] += v + bias[col];
                } else { // M_OUT (fp32 + bias)
                    Cf[(long long)row * N + col] = v + bias[col];
                }
            }
        }
    }
}

// ---------------------------------------------------------------------------
__global__ __launch_bounds__(256)
void cvt_bf16_k(const float* __restrict__ in, bf16* __restrict__ out, int n4)
{
    int i = blockIdx.x * 256 + threadIdx.x;
    if (i >= n4) return;
    float4 f = ((const float4*)in)[i];
    bf16x4 o = { (bf16)f.x, (bf16)f.y, (bf16)f.z, (bf16)f.w };
    ((bf16x4*)out)[i] = o;
}

// out[l][c][r] = (bf16) in[l][r][c]   (n x n per layer, n mult of 32)
__global__ __launch_bounds__(256)
void transpose_cvt_k(const float* __restrict__ in, bf16* __restrict__ out, int n)
{
    __shared__ float t[32][33];
    const int l = blockIdx.z;
    const int r0 = blockIdx.y * 32, c0 = blockIdx.x * 32;
    const float* src = in + (long long)l * n * n;
    bf16* dst = out + (long long)l * n * n;
    const int tx = threadIdx.x & 31, ty = threadIdx.x >> 5;   // 32x8
#pragma unroll
    for (int i = 0; i < 32; i += 8)
        t[ty + i][tx] = src[(long long)(r0 + ty + i) * n + c0 + tx];
    __syncthreads();
#pragma unroll
    for (int i = 0; i < 32; i += 8)
        dst[(long long)(c0 + ty + i) * n + r0 + tx] = (bf16)t[tx][ty + i];
}

// merged bias: bm[l][a] = sum_j o2w[l][a][j]*o1b[l][j] + o2b[l][a]; one wave per (l,a)
__global__ __launch_bounds__(256)
void bias_merge_k(const float* __restrict__ o2w, const float* __restrict__ o1b,
                  const float* __restrict__ o2b, float* __restrict__ bm, int total)
{
    const int wid = threadIdx.x >> 6, lane = threadIdx.x & 63;
    const int idx = blockIdx.x * 4 + wid;
    if (idx >= total) return;
    const int l = idx / 768, a = idx - l * 768;
    const float* wrow = o2w + ((long long)l * 768 + a) * 768;
    const float* brow = o1b + (long long)l * 768;
    float s = 0.f;
#pragma unroll
    for (int j = 0; j < 12; ++j) {
        int c = j * 64 + lane;
        s += wrow[c] * brow[c];
    }
#pragma unroll
    for (int o = 32; o; o >>= 1) s += __shfl_down(s, o);
    if (lane == 0) bm[idx] = s + o2b[(long long)l * 768 + a];
}

__global__ __launch_bounds__(256)
void cond_proj_k(const float* __restrict__ label, const float* __restrict__ sw,
                 const float* __restrict__ bw, float* __restrict__ scale,
                 float* __restrict__ bias, int total)
{
    int idx = blockIdx.x * 256 + threadIdx.x;
    if (idx >= total) return;
    int l = idx / 6144;
    int rem = idx - l * 6144;
    int b = rem / 768, d = rem - (rem / 768) * 768;
    const float* lab = label + b * 17;
    const float* swp = sw + ((long long)l * 768 + d) * 17;
    const float* bwp = bw + ((long long)l * 768 + d) * 17;
    float s = 0.f, bb = 0.f;
#pragma unroll
    for (int c = 0; c < 17; ++c) { float lv = lab[c]; s += lv * swp[c]; bb += lv * bwp[c]; }
    scale[idx] = s;
    bias[idx]  = bb;
}

// h[b,s,:] = (s==0 ? sos : xe[b,s-1,:]) + pos_bias(s)
__global__ __launch_bounds__(256)
void shift_pos_k(const float* __restrict__ xe, const float* __restrict__ sos,
                 const float* __restrict__ p0, const float* __restrict__ p1,
                 const float* __restrict__ p2, float* __restrict__ h)
{
    const int s = blockIdx.x, b = blockIdx.y;
    const int i0 = s >> 8, i1 = (s >> 4) & 15, i2 = s & 15;
    const float* xr = xe + ((long long)b * 1024 + (s - 1)) * 768;
#pragma unroll
    for (int j = 0; j < 3; ++j) {
        const int d = j * 256 + threadIdx.x;
        float v = (s == 0) ? sos[d] : xr[d];
        float pbv = (d < 256) ? p0[i0 * 256 + d]
                  : (d < 512) ? p1[i1 * 256 + (d - 256)]
                              : p2[i2 * 256 + (d - 512)];
        h[((long long)b * 1024 + s) * 768 + d] = v + pbv;
    }
}

// conditional LayerNorm, float4-vectorized (192 active lanes of 256)
__global__ __launch_bounds__(256)
void cond_ln_k(const float* __restrict__ h, const float* __restrict__ scale,
               const float* __restrict__ bias, bf16* __restrict__ out)
{
    const long long row = (long long)blockIdx.y * 1024 + blockIdx.x;
    const int b = blockIdx.y;
    const int t = threadIdx.x;
    const float4* hr4 = (const float4*)(h + row * 768);
    float4 v = make_float4(0.f, 0.f, 0.f, 0.f);
    if (t < 192) v = hr4[t];
    float sum = v.x + v.y + v.z + v.w;
    float sq  = v.x * v.x + v.y * v.y + v.z * v.z + v.w * v.w;
    __shared__ float sm[8];
#pragma unroll
    for (int o = 32; o; o >>= 1) { sum += __shfl_down(sum, o); sq += __shfl_down(sq, o); }
    const int wid = t >> 6;
    if ((t & 63) == 0) { sm[wid] = sum; sm[4 + wid] = sq; }
    __syncthreads();
    sum = sm[0] + sm[1] + sm[2] + sm[3];
    sq  = sm[4] + sm[5] + sm[6] + sm[7];
    const float mean = sum * (1.f / 768.f);
    const float var  = sq * (1.f / 768.f) - mean * mean;
    const float rs   = rsqrtf(var + 1e-6f);
    if (t < 192) {
        const float4 sc = ((const float4*)(scale + (long long)b * 768))[t];
        const float4 bi = ((const float4*)(bias  + (long long)b * 768))[t];
        bf16x4 o4 = { (bf16)((v.x - mean) * rs * (1.f + sc.x) + bi.x),
                      (bf16)((v.y - mean) * rs * (1.f + sc.y) + bi.y),
                      (bf16)((v.z - mean) * rs * (1.f + sc.z) + bi.z),
                      (bf16)((v.w - mean) * rs * (1.f + sc.w) + bi.w) };
        ((bf16x4*)(out + row * 768))[t] = o4;
    }
}

// causal softmax over row i. Touches only cols < ceil64(i+1).
__global__ __launch_bounds__(256)
void softmax_k(bf16* __restrict__ P)
{
    const int i = blockIdx.x, b = blockIdx.y;
    bf16* row = P + ((long long)b * 1024 + i) * 1024;
    const int len = i + 1;
    const int lim = (i | 63) + 1;          // 64-col boundary PV can read up to
    float v[4], mx = -1e30f;
#pragma unroll
    for (int j = 0; j < 4; ++j) {
        int c = j * 256 + threadIdx.x;
        v[j] = (c < len) ? (float)row[c] : -1e30f;
        mx = fmaxf(mx, v[j]);
    }
    __shared__ float sm[8];
#pragma unroll
    for (int o = 32; o; o >>= 1) mx = fmaxf(mx, __shfl_down(mx, o));
    const int wid = threadIdx.x >> 6;
    if ((threadIdx.x & 63) == 0) sm[wid] = mx;
    __syncthreads();
    mx = fmaxf(fmaxf(sm[0], sm[1]), fmaxf(sm[2], sm[3]));
    float s = 0.f;
#pragma unroll
    for (int j = 0; j < 4; ++j) {
        v[j] = __expf(v[j] - mx);
        s += ((j * 256 + threadIdx.x) < len) ? v[j] : 0.f;
    }
#pragma unroll
    for (int o = 32; o; o >>= 1) s += __shfl_down(s, o);
    if ((threadIdx.x & 63) == 0) sm[4 + wid] = s;
    __syncthreads();
    s = sm[4] + sm[5] + sm[6] + sm[7];
    const float inv = 1.f / s;
#pragma unroll
    for (int j = 0; j < 4; ++j) {
        int c = j * 256 + threadIdx.x;
        if (c < lim) row[c] = (c < len) ? (bf16)(v[j] * inv) : (bf16)0.f;
    }
}

__global__ __launch_bounds__(256)
void fill_k(float* o, int n, float v)
{
    int i = blockIdx.x * 256 + threadIdx.x;
    if (i < n) o[i] = v;
}

// ---------------------------------------------------------------------------
extern "C" void kernel_launch(void* const* d_in, const int* in_sizes, int n_in,
                              void* d_out, int out_size, void* d_ws, size_t ws_size,
                              hipStream_t stream)
{
    (void)in_sizes; (void)n_in;
    const float* x     = (const float*)d_in[0];
    const float* label = (const float*)d_in[2];
    const float* dw    = (const float*)d_in[3];
    const float* db    = (const float*)d_in[4];
    const float* sos   = (const float*)d_in[5];
    const float* p0    = (const float*)d_in[6];
    const float* p1    = (const float*)d_in[7];
    const float* p2    = (const float*)d_in[8];
    const float* ln1sw = (const float*)d_in[9];
    const float* ln1bw = (const float*)d_in[10];
    const float* qkvw  = (const float*)d_in[11];
    const float* qkvb  = (const float*)d_in[12];
    const float* ao1w  = (const float*)d_in[13];
    const float* ao1b  = (const float*)d_in[14];
    const float* ao2w  = (const float*)d_in[15];
    const float* ao2b  = (const float*)d_in[16];
    const float* ln2sw = (const float*)d_in[17];
    const float* ln2bw = (const float*)d_in[18];
    const float* m1w   = (const float*)d_in[19];
    const float* m1b   = (const float*)d_in[20];
    const float* m2w   = (const float*)d_in[21];
    const float* m2b   = (const float*)d_in[22];
    const float* lnfsw = (const float*)d_in[23];
    const float* lnfbw = (const float*)d_in[24];
    const float* outw  = (const float*)d_in[25];
    const float* outb  = (const float*)d_in[26];
    float* out = (float*)d_out;

    char* p = (char*)d_ws;
    auto alloc = [&](size_t bytes) { void* r = (void*)p; p += (bytes + 255) & ~(size_t)255; return r; };
    float* h    = (float*)alloc(8192LL * 768 * 4);
    bf16*  hn   = (bf16*) alloc(8192LL * 768 * 2);
    bf16*  q    = (bf16*) alloc(8192LL * 768 * 2);
    bf16*  kbuf = (bf16*) alloc(8192LL * 768 * 2);
    bf16*  vT   = (bf16*) alloc(8192LL * 768 * 2);   // [B,768,1024]
    bf16*  P    = (bf16*) alloc(8LL * 1024 * 1024 * 2);
    bf16*  attn = (bf16*) alloc(8192LL * 768 * 2);
    bf16*  mb   = (bf16*) alloc(8192LL * 3072 * 2);
    bf16*  wout = (bf16*) alloc(1024LL * 768 * 2);
    bf16*  wmA  = (bf16*) alloc(12LL * 768 * 768 * 2);   // merged o2@o1, bf16
    float* bmA  = (float*)alloc(12LL * 768 * 4);         // merged o-bias
    float* s1   = (float*)alloc(12LL * 8 * 768 * 4);
    float* b1   = (float*)alloc(12LL * 8 * 768 * 4);
    float* s2   = (float*)alloc(12LL * 8 * 768 * 4);
    float* b2   = (float*)alloc(12LL * 8 * 768 * 4);
    float* sf   = (float*)alloc(8LL * 768 * 4);
    float* bfb  = (float*)alloc(8LL * 768 * 4);

    size_t base_needed = (size_t)(p - (char*)d_ws);
    if (base_needed + 16LL * 1024 * 1024 > ws_size) {
        fill_k<<<(out_size + 255) / 256, 256, 0, stream>>>(out, out_size, 1e9f);
        return;
    }

    const long long SZ_QKV = 2304LL * 768, SZ_O = 768LL * 768, SZ_M = 3072LL * 768;
    size_t all_bytes = (size_t)(12 * (SZ_QKV + 2 * SZ_M)) * 2;
    bool allw = ((size_t)(p - (char*)d_ws) + all_bytes + 4096 <= ws_size);

    bf16 *wqkvA, *wm1A, *wm2A;
    if (allw) {
        wqkvA = (bf16*)alloc(12 * SZ_QKV * 2);
        wm1A  = (bf16*)alloc(12 * SZ_M * 2);
        wm2A  = (bf16*)alloc(12 * SZ_M * 2);
    } else {
        wqkvA = (bf16*)alloc(SZ_QKV * 2);
        wm1A  = (bf16*)alloc(SZ_M * 2);
        wm2A  = (bf16*)alloc(SZ_M * 2);
    }

    // one-time scratch aliased onto regions unused until the layer loop:
    bf16*  xbf   = (bf16*)P;
    bf16*  dwbf  = (bf16*)P + 524288;
    bf16*  wo2bf = (bf16*)P + 1048576;
    float* xe    = (float*)mb;
    bf16*  o1t   = mb + 12582912;

    // --- one-time precompute ---
    cvt_bf16_k<<<1024 * 768 / 4 / 256, 256, 0, stream>>>(outw, wout, 1024 * 768 / 4);
    cond_proj_k<<<(12 * 8 * 768 + 255) / 256, 256, 0, stream>>>(label, ln1sw, ln1bw, s1, b1, 12 * 8 * 768);
    cond_proj_k<<<(12 * 8 * 768 + 255) / 256, 256, 0, stream>>>(label, ln2sw, ln2bw, s2, b2, 12 * 8 * 768);
    cond_proj_k<<<(8 * 768 + 255) / 256, 256, 0, stream>>>(label, lnfsw, lnfbw, sf, bfb, 8 * 768);

    if (allw) {
        cvt_bf16_k<<<(int)(12 * SZ_QKV / 4 / 256), 256, 0, stream>>>(qkvw, wqkvA, (int)(12 * SZ_QKV / 4));
        cvt_bf16_k<<<(int)(12 * SZ_M / 4 / 256),   256, 0, stream>>>(m1w,  wm1A,  (int)(12 * SZ_M / 4));
        cvt_bf16_k<<<(int)(12 * SZ_M / 4 / 256),   256, 0, stream>>>(m2w,  wm2A,  (int)(12 * SZ_M / 4));
    }

    // merged out-proj: Wm[l] = o2[l] @ o1[l]  (bf16), bm[l] = o2[l]@o1b[l] + o2b[l]
    cvt_bf16_k<<<(int)(12 * SZ_O / 4 / 256), 256, 0, stream>>>(ao2w, wo2bf, (int)(12 * SZ_O / 4));
    transpose_cvt_k<<<dim3(24, 24, 12), 256, 0, stream>>>(ao1w, o1t, 768);
    gemm_k<M_WM><<<dim3(6, 6, 12), 256, 49152, stream>>>(
        wo2bf, o1t, 768, 768, 768, SZ_O, SZ_O, SZ_O,
        nullptr, wmA, nullptr, nullptr, nullptr, nullptr);
    bias_merge_k<<<(12 * 768 + 3) / 4, 256, 0, stream>>>(ao2w, ao1b, ao2b, bmA, 12 * 768);

    // embed: x->bf16, xe = x @ dw^T + db (fp32), then shift+pos
    cvt_bf16_k<<<8192 * 64 / 4 / 256, 256, 0, stream>>>(x, xbf, 8192 * 64 / 4);
    cvt_bf16_k<<<768 * 64 / 4 / 256, 256, 0, stream>>>(dw, dwbf, 768 * 64 / 4);
    gemm_k<M_OUT><<<dim3(64, 6, 1), 256, 49152, stream>>>(
        xbf, dwbf, 8192, 768, 64, 0, 0, 0, db, nullptr, xe, nullptr, nullptr, nullptr);
    shift_pos_k<<<dim3(1024, 8), 256, 0, stream>>>(xe, sos, p0, p1, p2, h);

    for (int l = 0; l < 12; ++l) {
        bf16 *wqkv, *wm1, *wm2;
        if (allw) {
            wqkv = wqkvA + (long long)l * SZ_QKV;
            wm1  = wm1A  + (long long)l * SZ_M;
            wm2  = wm2A  + (long long)l * SZ_M;
        } else {
            wqkv = wqkvA; wm1 = wm1A; wm2 = wm2A;
            cvt_bf16_k<<<(int)(SZ_QKV / 4 / 256), 256, 0, stream>>>(qkvw + (long long)l * SZ_QKV, wqkv, (int)(SZ_QKV / 4));
            cvt_bf16_k<<<(int)(SZ_M / 4 / 256),   256, 0, stream>>>(m1w  + (long long)l * SZ_M,   wm1,  (int)(SZ_M / 4));
            cvt_bf16_k<<<(int)(SZ_M / 4 / 256),   256, 0, stream>>>(m2w  + (long long)l * SZ_M,   wm2,  (int)(SZ_M / 4));
        }

        cond_ln_k<<<dim3(1024, 8), 256, 0, stream>>>(h, s1 + (long long)l * 6144, b1 + (long long)l * 6144, hn);

        gemm_k<M_QKV><<<dim3(64, 18, 1), 256, 49152, stream>>>(
            hn, wqkv, 8192, 2304, 768, 0, 0, 0,
            qkvb + (long long)l * 2304, nullptr, nullptr, q, kbuf, vT);

        gemm64_k<M_SCORES><<<dim3(16, 8, 8), 256, 49152, stream>>>(
            q, kbuf, 1024, 1024, 768, 1024LL * 768, 1024LL * 768, 1024LL * 1024,
            nullptr, P, nullptr);

        softmax_k<<<dim3(1024, 8), 256, 0, stream>>>(P);

        gemm64_k<M_PV><<<dim3(16, 6, 8), 256, 49152, stream>>>(
            P, vT, 1024, 768, 1024, 1024LL * 1024, 768LL * 1024, 1024LL * 768,
            nullptr, attn, nullptr);

        // merged out-proj (o2@o1 fused), residual add into h
        gemm64_k<M_RESID><<<dim3(128, 6, 1), 256, 49152, stream>>>(
            attn, wmA + (long long)l * SZ_O, 8192, 768, 768, 0, 0, 0,
            bmA + (long long)l * 768, nullptr, h);

        cond_ln_k<<<dim3(1024, 8), 256, 0, stream>>>(h, s2 + (long long)l * 6144, b2 + (long long)l * 6144, hn);

        gemm_k<M_GELU><<<dim3(64, 24, 1), 256, 49152, stream>>>(
            hn, wm1, 8192, 3072, 768, 0, 0, 0,
            m1b + (long long)l * 3072, mb, nullptr, nullptr, nullptr, nullptr);

        gemm64_k<M_RESID><<<dim3(128, 6, 1), 256, 49152, stream>>>(
            mb, wm2, 8192, 768, 3072, 0, 0, 0,
            m2b + (long long)l * 768, nullptr, h);
    }

    cond_ln_k<<<dim3(1024, 8), 256, 0, stream>>>(h, sf, bfb, hn);
    gemm64_k<M_OUT><<<dim3(128, 8, 1), 256, 49152, stream>>>(
        hn, wout, 8192, 1024, 768, 0, 0, 0,
        outb, nullptr, out);
}

// Round 13
// 3722.564 us; speedup vs baseline: 1.4368x; 1.0461x over previous
//
#include <hip/hip_runtime.h>

typedef __bf16 bf16;
typedef __bf16 bf16x8 __attribute__((ext_vector_type(8)));
typedef __bf16 bf16x4 __attribute__((ext_vector_type(4)));
typedef float  f32x4  __attribute__((ext_vector_type(4)));

#define DEV __device__ __forceinline__

// async global->LDS, 16B per lane; lds dest must be wave-uniform base (HW adds lane*16)
DEV void gload_lds16(const bf16* g, bf16* l) {
    __builtin_amdgcn_global_load_lds(
        (__attribute__((address_space(1))) void*)g,
        (__attribute__((address_space(3))) void*)l, 16, 0, 0);
}

// lgkmcnt(0) first: wave's own ds_reads complete before the barrier, so the
// next buffer-overwrite (gload_lds) can never race an in-flight read.
DEV void barrier_raw() {
    asm volatile("s_waitcnt lgkmcnt(0)" ::: "memory");
    __builtin_amdgcn_s_barrier();
    asm volatile("" ::: "memory");
}

enum { M_QKV, M_SCORES, M_PVRESID, M_RESID, M_GELU, M_OUT, M_WM, M_VMT };

// ---------------------------------------------------------------------------
// 128x128 tile GEMM: A+B in LDS, 3-buffer 2-ahead counted-vmcnt. LDS 48KB.
// C[m,n] = sum_k A[m,k]*B[n,k]; A:[M,K], B:[N,K] bf16 row-major.
// ---------------------------------------------------------------------------
template<int MODE>
__global__ __launch_bounds__(256)
void gemm_k(const bf16* __restrict__ A, const bf16* __restrict__ B,
            int M, int N, int K,
            long long batchA, long long batchB, long long batchC,
            const float* __restrict__ bias,
            bf16* __restrict__ Cb, float* __restrict__ Cf,
            bf16* __restrict__ qp, bf16* __restrict__ kp, bf16* __restrict__ vp)
{
    const int bm = blockIdx.x, bn = blockIdx.y, bz = blockIdx.z;
    const int kTiles = K >> 5;

    const int tid = threadIdx.x, wid = tid >> 6, lane = tid & 63;
    const bf16* Ab = A + (long long)bz * batchA + (long long)bm * 128 * K;
    const bf16* Bb = B + (long long)bz * batchB + (long long)bn * 128 * K;

    extern __shared__ __align__(16) bf16 smem[];   // 24576 elems = 48KB
    bf16* sA = smem;            // [3][4096]
    bf16* sB = smem + 12288;    // [3][4096]

    const int srow = wid * 16 + (lane >> 2);
    const int scol = (lane & 3) * 8;
    const long long aoff = (long long)srow * K + scol;

    auto stage = [&](int buf, int kt) {
        const bf16* ga = Ab + (long long)kt * 32;
        const bf16* gb = Bb + (long long)kt * 32;
        bf16* a = sA + buf * 4096;
        bf16* b = sB + buf * 4096;
        gload_lds16(ga + aoff,            a + (wid * 16) * 32);
        gload_lds16(ga + aoff + 64LL * K, a + (64 + wid * 16) * 32);
        gload_lds16(gb + aoff,            b + (wid * 16) * 32);
        gload_lds16(gb + aoff + 64LL * K, b + (64 + wid * 16) * 32);
    };

    f32x4 acc[4][4];
#pragma unroll
    for (int m = 0; m < 4; ++m)
#pragma unroll
        for (int n = 0; n < 4; ++n) acc[m][n] = (f32x4){0.f, 0.f, 0.f, 0.f};

    const int npre = kTiles < 2 ? kTiles : 2;
    for (int t = 0; t < npre; ++t) stage(t, t);

    const int wr = wid >> 1, wc = wid & 1;
    const int arow = wr * 64 + (lane & 15);
    const int brow = wc * 64 + (lane & 15);
    const int koff = (lane >> 4) * 8;

    int cur = 0;
    for (int kt = 0; kt < kTiles; ++kt) {
        if (kt + 1 < kTiles) asm volatile("s_waitcnt vmcnt(4)" ::: "memory");
        else                 asm volatile("s_waitcnt vmcnt(0)" ::: "memory");
        barrier_raw();
        if (kt + 2 < kTiles) {
            int ib = cur - 1; if (ib < 0) ib = 2;   // (cur+2)%3
            stage(ib, kt + 2);
        }

        const bf16* a = sA + cur * 4096;
        const bf16* b = sB + cur * 4096;
        bf16x8 af[4], bfr[4];
#pragma unroll
        for (int m = 0; m < 4; ++m)
            af[m] = *(const bf16x8*)&a[(arow + m * 16) * 32 + koff];
#pragma unroll
        for (int n = 0; n < 4; ++n)
            bfr[n] = *(const bf16x8*)&b[(brow + n * 16) * 32 + koff];
#pragma unroll
        for (int m = 0; m < 4; ++m)
#pragma unroll
            for (int n = 0; n < 4; ++n)
                acc[m][n] = __builtin_amdgcn_mfma_f32_16x16x32_bf16(af[m], bfr[n], acc[m][n], 0, 0, 0);

        cur = (cur == 2) ? 0 : cur + 1;
    }

    // C/D layout: col = lane&15, row = (lane>>4)*4 + r   [learn_hip m89]
    const int cr0 = bm * 128 + wr * 64 + (lane >> 4) * 4;
    const int cc0 = bn * 128 + wc * 64 + (lane & 15);
#pragma unroll
    for (int m = 0; m < 4; ++m) {
#pragma unroll
        for (int n = 0; n < 4; ++n) {
            const int col = cc0 + n * 16;
#pragma unroll
            for (int r = 0; r < 4; ++r) {
                const int row = cr0 + m * 16 + r;
                float v = acc[m][n][r];
                if (MODE == M_QKV) {
                    v += bias[col];
                    int hd = col / 192, rr = col % 192;
                    if (rr < 64)
                        qp[(long long)row * 768 + hd * 64 + rr] = (bf16)(v * 0.03608439182435161f);
                    else if (rr < 128)
                        kp[(long long)row * 768 + hd * 64 + (rr - 64)] = (bf16)v;
                    else  // v written STRAIGHT (coalesced); transpose happens in Vm epilogue
                        vp[(long long)row * 768 + hd * 64 + (rr - 128)] = (bf16)v;
                } else if (MODE == M_GELU) {
                    float xg = v + bias[col];
                    Cb[(long long)row * N + col] = (bf16)(xg / (1.f + __expf(-1.702f * xg)));
                } else if (MODE == M_RESID) {
                    long long idx = (long long)row * N + col;
                    Cf[idx] += v + bias[col];
                } else if (MODE == M_WM) {
                    Cb[(long long)bz * batchC + (long long)row * N + col] = (bf16)v;
                } else { // M_OUT (fp32 + bias)
                    Cf[(long long)row * N + col] = v + bias[col];
                }
            }
        }
    }
}

// ---------------------------------------------------------------------------
// 64x128 tile GEMM — 4-buffer 3-ahead counted-vmcnt, LDS 48KB -> 3 blocks/CU.
// Modes: scores (causal skip), PV+residual (causal trunc, h +=), Vm
// (transposed scatter), plain residual, fp32 out.
// ---------------------------------------------------------------------------
template<int MODE>
__global__ __launch_bounds__(256)
void gemm64_k(const bf16* __restrict__ A, const bf16* __restrict__ B,
              int M, int N, int K,
              long long batchA, long long batchB, long long batchC,
              const float* __restrict__ bias,
              bf16* __restrict__ Cb, float* __restrict__ Cf)
{
    const int bm = blockIdx.x, bn = blockIdx.y, bz = blockIdx.z;
    if (MODE == M_SCORES && 2 * bn > bm) return;     // fully-masked tile
    int kTiles = K >> 5;
    if (MODE == M_PVRESID) {                         // P[:,k]==0 for k>row
        int lim = 2 * bm + 2;
        if (lim < kTiles) kTiles = lim;
    }

    const int tid = threadIdx.x, wid = tid >> 6, lane = tid & 63;
    const bf16* Ab = A + (long long)bz * batchA + (long long)bm * 64 * K;
    const bf16* Bb = B + (long long)bz * batchB + (long long)bn * 128 * K;

    extern __shared__ __align__(16) bf16 smem[];   // 24576 elems = 48KB
    bf16* sA = smem;            // [4][2048]
    bf16* sB = smem + 8192;     // [4][4096]

    const int srow = wid * 16 + (lane >> 2);          // 0..63
    const int scol = (lane & 3) * 8;
    const long long aoff = (long long)srow * K + scol;

    auto stage = [&](int buf, int kt) {
        const bf16* ga = Ab + (long long)kt * 32;
        const bf16* gb = Bb + (long long)kt * 32;
        gload_lds16(ga + aoff,            sA + buf * 2048 + (wid * 16) * 32);
        gload_lds16(gb + aoff,            sB + buf * 4096 + (wid * 16) * 32);
        gload_lds16(gb + aoff + 64LL * K, sB + buf * 4096 + (64 + wid * 16) * 32);
    };

    f32x4 acc[2][4];
#pragma unroll
    for (int m = 0; m < 2; ++m)
#pragma unroll
        for (int n = 0; n < 4; ++n) acc[m][n] = (f32x4){0.f, 0.f, 0.f, 0.f};

    const int npre = kTiles < 3 ? kTiles : 3;
    for (int t = 0; t < npre; ++t) stage(t, t);

    const int wr = wid >> 1, wc = wid & 1;
    const int arow = wr * 32 + (lane & 15);
    const int brow = wc * 64 + (lane & 15);
    const int koff = (lane >> 4) * 8;

    for (int kt = 0; kt < kTiles; ++kt) {
        const int rem = kTiles - 1 - kt;
        if (rem >= 2)      asm volatile("s_waitcnt vmcnt(6)" ::: "memory");
        else if (rem == 1) asm volatile("s_waitcnt vmcnt(3)" ::: "memory");
        else               asm volatile("s_waitcnt vmcnt(0)" ::: "memory");
        barrier_raw();
        if (kt + 3 < kTiles) stage((kt + 3) & 3, kt + 3);

        const int cur = kt & 3;
        const bf16* a = sA + cur * 2048;
        const bf16* b = sB + cur * 4096;
        bf16x8 af[2], bfr[4];
#pragma unroll
        for (int m = 0; m < 2; ++m)
            af[m] = *(const bf16x8*)&a[(arow + m * 16) * 32 + koff];
#pragma unroll
        for (int n = 0; n < 4; ++n)
            bfr[n] = *(const bf16x8*)&b[(brow + n * 16) * 32 + koff];
#pragma unroll
        for (int m = 0; m < 2; ++m)
#pragma unroll
            for (int n = 0; n < 4; ++n)
                acc[m][n] = __builtin_amdgcn_mfma_f32_16x16x32_bf16(af[m], bfr[n], acc[m][n], 0, 0, 0);
    }

    const int cr0 = bm * 64 + wr * 32 + (lane >> 4) * 4;
    const int cc0 = bn * 128 + wc * 64 + (lane & 15);
#pragma unroll
    for (int m = 0; m < 2; ++m) {
#pragma unroll
        for (int n = 0; n < 4; ++n) {
            const int col = cc0 + n * 16;
#pragma unroll
            for (int r = 0; r < 4; ++r) {
                const int row = cr0 + m * 16 + r;
                float v = acc[m][n][r];
                if (MODE == M_SCORES) {
                    Cb[(long long)bz * batchC + (long long)row * N + col] = (bf16)v;
                } else if (MODE == M_PVRESID) {
                    long long grow = (long long)bz * 1024 + row;
                    Cf[grow * 768 + col] += v + bias[col];
                } else if (MODE == M_VMT) {
                    // Vm = V @ Wm^T, stored transposed per batch: vmT[b, col, s]
                    long long b2 = row >> 10, s = row & 1023;
                    Cb[(b2 * 768 + col) * 1024 + s] = (bf16)v;
                } else if (MODE == M_RESID) {
                    long long idx = (long long)row * N + col;
                    Cf[idx] += v + bias[col];
                } else { // M_OUT (fp32 + bias)
                    Cf[(long long)row * N + col] = v + bias[col];
                }
            }
        }
    }
}

// ---------------------------------------------------------------------------
__global__ __launch_bounds__(256)
void cvt_bf16_k(const float* __restrict__ in, bf16* __restrict__ out, int n4)
{
    int i = blockIdx.x * 256 + threadIdx.x;
    if (i >= n4) return;
    float4 f = ((const float4*)in)[i];
    bf16x4 o = { (bf16)f.x, (bf16)f.y, (bf16)f.z, (bf16)f.w };
    ((bf16x4*)out)[i] = o;
}

// out[l][c][r] = (bf16) in[l][r][c]   (n x n per layer, n mult of 32)
__global__ __launch_bounds__(256)
void transpose_cvt_k(const float* __restrict__ in, bf16* __restrict__ out, int n)
{
    __shared__ float t[32][33];
    const int l = blockIdx.z;
    const int r0 = blockIdx.y * 32, c0 = blockIdx.x * 32;
    const float* src = in + (long long)l * n * n;
    bf16* dst = out + (long long)l * n * n;
    const int tx = threadIdx.x & 31, ty = threadIdx.x >> 5;   // 32x8
#pragma unroll
    for (int i = 0; i < 32; i += 8)
        t[ty + i][tx] = src[(long long)(r0 + ty + i) * n + c0 + tx];
    __syncthreads();
#pragma unroll
    for (int i = 0; i < 32; i += 8)
        dst[(long long)(c0 + ty + i) * n + r0 + tx] = (bf16)t[tx][ty + i];
}

// merged bias: bm[l][a] = sum_j o2w[l][a][j]*o1b[l][j] + o2b[l][a]; one wave per (l,a)
__global__ __launch_bounds__(256)
void bias_merge_k(const float* __restrict__ o2w, const float* __restrict__ o1b,
                  const float* __restrict__ o2b, float* __restrict__ bm, int total)
{
    const int wid = threadIdx.x >> 6, lane = threadIdx.x & 63;
    const int idx = blockIdx.x * 4 + wid;
    if (idx >= total) return;
    const int l = idx / 768, a = idx - l * 768;
    const float* wrow = o2w + ((long long)l * 768 + a) * 768;
    const float* brow = o1b + (long long)l * 768;
    float s = 0.f;
#pragma unroll
    for (int j = 0; j < 12; ++j) {
        int c = j * 64 + lane;
        s += wrow[c] * brow[c];
    }
#pragma unroll
    for (int o = 32; o; o >>= 1) s += __shfl_down(s, o);
    if (lane == 0) bm[idx] = s + o2b[(long long)l * 768 + a];
}

__global__ __launch_bounds__(256)
void cond_proj_k(const float* __restrict__ label, const float* __restrict__ sw,
                 const float* __restrict__ bw, float* __restrict__ scale,
                 float* __restrict__ bias, int total)
{
    int idx = blockIdx.x * 256 + threadIdx.x;
    if (idx >= total) return;
    int l = idx / 6144;
    int rem = idx - l * 6144;
    int b = rem / 768, d = rem - (rem / 768) * 768;
    const float* lab = label + b * 17;
    const float* swp = sw + ((long long)l * 768 + d) * 17;
    const float* bwp = bw + ((long long)l * 768 + d) * 17;
    float s = 0.f, bb = 0.f;
#pragma unroll
    for (int c = 0; c < 17; ++c) { float lv = lab[c]; s += lv * swp[c]; bb += lv * bwp[c]; }
    scale[idx] = s;
    bias[idx]  = bb;
}

// h[b,s,:] = (s==0 ? sos : xe[b,s-1,:]) + pos_bias(s)
__global__ __launch_bounds__(256)
void shift_pos_k(const float* __restrict__ xe, const float* __restrict__ sos,
                 const float* __restrict__ p0, const float* __restrict__ p1,
                 const float* __restrict__ p2, float* __restrict__ h)
{
    const int s = blockIdx.x, b = blockIdx.y;
    const int i0 = s >> 8, i1 = (s >> 4) & 15, i2 = s & 15;
    const float* xr = xe + ((long long)b * 1024 + (s - 1)) * 768;
#pragma unroll
    for (int j = 0; j < 3; ++j) {
        const int d = j * 256 + threadIdx.x;
        float v = (s == 0) ? sos[d] : xr[d];
        float pbv = (d < 256) ? p0[i0 * 256 + d]
                  : (d < 512) ? p1[i1 * 256 + (d - 256)]
                              : p2[i2 * 256 + (d - 512)];
        h[((long long)b * 1024 + s) * 768 + d] = v + pbv;
    }
}

// conditional LayerNorm — one WAVE per row (4 rows/block, shuffle-only).
// lane holds 12 floats = 3x float4 at vec-index j*64+lane.
__global__ __launch_bounds__(256)
void cond_ln_k(const float* __restrict__ h, const float* __restrict__ scale,
               const float* __restrict__ bias, bf16* __restrict__ out)
{
    const int wid = threadIdx.x >> 6, lane = threadIdx.x & 63;
    const int b = blockIdx.y;
    const long long row = (long long)b * 1024 + blockIdx.x * 4 + wid;
    const float4* hr4 = (const float4*)(h + row * 768);
    float4 v[3];
    float sum = 0.f, sq = 0.f;
#pragma unroll
    for (int j = 0; j < 3; ++j) {
        v[j] = hr4[j * 64 + lane];
        sum += v[j].x + v[j].y + v[j].z + v[j].w;
        sq  += v[j].x * v[j].x + v[j].y * v[j].y + v[j].z * v[j].z + v[j].w * v[j].w;
    }
#pragma unroll
    for (int o = 32; o; o >>= 1) { sum += __shfl_down(sum, o); sq += __shfl_down(sq, o); }
    sum = __shfl(sum, 0);
    sq  = __shfl(sq, 0);
    const float mean = sum * (1.f / 768.f);
    const float var  = sq * (1.f / 768.f) - mean * mean;
    const float rs   = rsqrtf(var + 1e-6f);
    const float4* sc4 = (const float4*)(scale + (long long)b * 768);
    const float4* bi4 = (const float4*)(bias  + (long long)b * 768);
    bf16x4* o4 = (bf16x4*)(out + row * 768);
#pragma unroll
    for (int j = 0; j < 3; ++j) {
        const float4 sc = sc4[j * 64 + lane];
        const float4 bi = bi4[j * 64 + lane];
        bf16x4 o = { (bf16)((v[j].x - mean) * rs * (1.f + sc.x) + bi.x),
                     (bf16)((v[j].y - mean) * rs * (1.f + sc.y) + bi.y),
                     (bf16)((v[j].z - mean) * rs * (1.f + sc.z) + bi.z),
                     (bf16)((v[j].w - mean) * rs * (1.f + sc.w) + bi.w) };
        o4[j * 64 + lane] = o;
    }
}

// causal softmax — one WAVE per row (4 rows/block, shuffle-only, vec4 I/O).
// Touches only cols < lim = ceil64(i+1) (PV reads at most that far).
__global__ __launch_bounds__(256)
void softmax_k(bf16* __restrict__ P)
{
    const int wid = threadIdx.x >> 6, lane = threadIdx.x & 63;
    const int i = blockIdx.x * 4 + wid, b = blockIdx.y;
    bf16* row = P + ((long long)b * 1024 + i) * 1024;
    const int len = i + 1;
    const int lim = (i | 63) + 1;          // multiple of 64 -> vec4-aligned
    float v[4][4];
    float mx = -1e30f;
#pragma unroll
    for (int j = 0; j < 4; ++j) {
        const int c0 = (j * 64 + lane) * 4;
        bf16x4 pv = ((const bf16x4*)row)[j * 64 + lane];
#pragma unroll
        for (int e = 0; e < 4; ++e) {
            v[j][e] = (c0 + e < len) ? (float)pv[e] : -1e30f;
            mx = fmaxf(mx, v[j][e]);
        }
    }
#pragma unroll
    for (int o = 32; o; o >>= 1) mx = fmaxf(mx, __shfl_down(mx, o));
    mx = __shfl(mx, 0);
    float s = 0.f;
#pragma unroll
    for (int j = 0; j < 4; ++j)
#pragma unroll
        for (int e = 0; e < 4; ++e) {
            v[j][e] = __expf(v[j][e] - mx);   // exp(-1e30-mx)=0 for masked
            s += v[j][e];
        }
#pragma unroll
    for (int o = 32; o; o >>= 1) s += __shfl_down(s, o);
    s = __shfl(s, 0);
    const float inv = 1.f / s;
#pragma unroll
    for (int j = 0; j < 4; ++j) {
        const int c0 = (j * 64 + lane) * 4;
        if (c0 < lim) {
            bf16x4 o = { (bf16)(v[j][0] * inv), (bf16)(v[j][1] * inv),
                         (bf16)(v[j][2] * inv), (bf16)(v[j][3] * inv) };
            ((bf16x4*)row)[j * 64 + lane] = o;
        }
    }
}

__global__ __launch_bounds__(256)
void fill_k(float* o, int n, float v)
{
    int i = blockIdx.x * 256 + threadIdx.x;
    if (i < n) o[i] = v;
}

// ---------------------------------------------------------------------------
extern "C" void kernel_launch(void* const* d_in, const int* in_sizes, int n_in,
                              void* d_out, int out_size, void* d_ws, size_t ws_size,
                              hipStream_t stream)
{
    (void)in_sizes; (void)n_in;
    const float* x     = (const float*)d_in[0];
    const float* label = (const float*)d_in[2];
    const float* dw    = (const float*)d_in[3];
    const float* db    = (const float*)d_in[4];
    const float* sos   = (const float*)d_in[5];
    const float* p0    = (const float*)d_in[6];
    const float* p1    = (const float*)d_in[7];
    const float* p2    = (const float*)d_in[8];
    const float* ln1sw = (const float*)d_in[9];
    const float* ln1bw = (const float*)d_in[10];
    const float* qkvw  = (const float*)d_in[11];
    const float* qkvb  = (const float*)d_in[12];
    const float* ao1w  = (const float*)d_in[13];
    const float* ao1b  = (const float*)d_in[14];
    const float* ao2w  = (const float*)d_in[15];
    const float* ao2b  = (const float*)d_in[16];
    const float* ln2sw = (const float*)d_in[17];
    const float* ln2bw = (const float*)d_in[18];
    const float* m1w   = (const float*)d_in[19];
    const float* m1b   = (const float*)d_in[20];
    const float* m2w   = (const float*)d_in[21];
    const float* m2b   = (const float*)d_in[22];
    const float* lnfsw = (const float*)d_in[23];
    const float* lnfbw = (const float*)d_in[24];
    const float* outw  = (const float*)d_in[25];
    const float* outb  = (const float*)d_in[26];
    float* out = (float*)d_out;

    char* p = (char*)d_ws;
    auto alloc = [&](size_t bytes) { void* r = (void*)p; p += (bytes + 255) & ~(size_t)255; return r; };
    float* h    = (float*)alloc(8192LL * 768 * 4);
    bf16*  hn   = (bf16*) alloc(8192LL * 768 * 2);
    bf16*  q    = (bf16*) alloc(8192LL * 768 * 2);
    bf16*  kbuf = (bf16*) alloc(8192LL * 768 * 2);
    bf16*  vbuf = (bf16*) alloc(8192LL * 768 * 2);   // V straight [B*S, 768]
    bf16*  vmT  = (bf16*) alloc(8192LL * 768 * 2);   // (V@Wm^T)^T per batch [B,768,1024]
    bf16*  P    = (bf16*) alloc(8LL * 1024 * 1024 * 2);
    bf16*  mb   = (bf16*) alloc(8192LL * 3072 * 2);
    bf16*  wout = (bf16*) alloc(1024LL * 768 * 2);
    bf16*  wmA  = (bf16*) alloc(12LL * 768 * 768 * 2);   // merged o2@o1, bf16
    float* bmA  = (float*)alloc(12LL * 768 * 4);         // merged o-bias
    float* s1   = (float*)alloc(12LL * 8 * 768 * 4);
    float* b1   = (float*)alloc(12LL * 8 * 768 * 4);
    float* s2   = (float*)alloc(12LL * 8 * 768 * 4);
    float* b2   = (float*)alloc(12LL * 8 * 768 * 4);
    float* sf   = (float*)alloc(8LL * 768 * 4);
    float* bfb  = (float*)alloc(8LL * 768 * 4);

    size_t base_needed = (size_t)(p - (char*)d_ws);
    if (base_needed + 16LL * 1024 * 1024 > ws_size) {
        fill_k<<<(out_size + 255) / 256, 256, 0, stream>>>(out, out_size, 1e9f);
        return;
    }

    const long long SZ_QKV = 2304LL * 768, SZ_O = 768LL * 768, SZ_M = 3072LL * 768;
    size_t all_bytes = (size_t)(12 * (SZ_QKV + 2 * SZ_M)) * 2;
    bool allw = ((size_t)(p - (char*)d_ws) + all_bytes + 4096 <= ws_size);

    bf16 *wqkvA, *wm1A, *wm2A;
    if (allw) {
        wqkvA = (bf16*)alloc(12 * SZ_QKV * 2);
        wm1A  = (bf16*)alloc(12 * SZ_M * 2);
        wm2A  = (bf16*)alloc(12 * SZ_M * 2);
    } else {
        wqkvA = (bf16*)alloc(SZ_QKV * 2);
        wm1A  = (bf16*)alloc(SZ_M * 2);
        wm2A  = (bf16*)alloc(SZ_M * 2);
    }

    // one-time scratch aliased onto regions unused until the layer loop:
    bf16*  xbf   = (bf16*)P;
    bf16*  dwbf  = (bf16*)P + 524288;
    bf16*  wo2bf = (bf16*)P + 1048576;
    float* xe    = (float*)mb;
    bf16*  o1t   = mb + 12582912;

    // --- one-time precompute ---
    cvt_bf16_k<<<1024 * 768 / 4 / 256, 256, 0, stream>>>(outw, wout, 1024 * 768 / 4);
    cond_proj_k<<<(12 * 8 * 768 + 255) / 256, 256, 0, stream>>>(label, ln1sw, ln1bw, s1, b1, 12 * 8 * 768);
    cond_proj_k<<<(12 * 8 * 768 + 255) / 256, 256, 0, stream>>>(label, ln2sw, ln2bw, s2, b2, 12 * 8 * 768);
    cond_proj_k<<<(8 * 768 + 255) / 256, 256, 0, stream>>>(label, lnfsw, lnfbw, sf, bfb, 8 * 768);

    if (allw) {
        cvt_bf16_k<<<(int)(12 * SZ_QKV / 4 / 256), 256, 0, stream>>>(qkvw, wqkvA, (int)(12 * SZ_QKV / 4));
        cvt_bf16_k<<<(int)(12 * SZ_M / 4 / 256),   256, 0, stream>>>(m1w,  wm1A,  (int)(12 * SZ_M / 4));
        cvt_bf16_k<<<(int)(12 * SZ_M / 4 / 256),   256, 0, stream>>>(m2w,  wm2A,  (int)(12 * SZ_M / 4));
    }

    // merged out-proj: Wm[l] = o2[l] @ o1[l]  (bf16), bm[l] = o2[l]@o1b[l] + o2b[l]
    cvt_bf16_k<<<(int)(12 * SZ_O / 4 / 256), 256, 0, stream>>>(ao2w, wo2bf, (int)(12 * SZ_O / 4));
    transpose_cvt_k<<<dim3(24, 24, 12), 256, 0, stream>>>(ao1w, o1t, 768);
    gemm_k<M_WM><<<dim3(6, 6, 12), 256, 49152, stream>>>(
        wo2bf, o1t, 768, 768, 768, SZ_O, SZ_O, SZ_O,
        nullptr, wmA, nullptr, nullptr, nullptr, nullptr);
    bias_merge_k<<<(12 * 768 + 3) / 4, 256, 0, stream>>>(ao2w, ao1b, ao2b, bmA, 12 * 768);

    // embed: x->bf16, xe = x @ dw^T + db (fp32), then shift+pos
    cvt_bf16_k<<<8192 * 64 / 4 / 256, 256, 0, stream>>>(x, xbf, 8192 * 64 / 4);
    cvt_bf16_k<<<768 * 64 / 4 / 256, 256, 0, stream>>>(dw, dwbf, 768 * 64 / 4);
    gemm_k<M_OUT><<<dim3(64, 6, 1), 256, 49152, stream>>>(
        xbf, dwbf, 8192, 768, 64, 0, 0, 0, db, nullptr, xe, nullptr, nullptr, nullptr);
    shift_pos_k<<<dim3(1024, 8), 256, 0, stream>>>(xe, sos, p0, p1, p2, h);

    for (int l = 0; l < 12; ++l) {
        bf16 *wqkv, *wm1, *wm2;
        if (allw) {
            wqkv = wqkvA + (long long)l * SZ_QKV;
            wm1  = wm1A  + (long long)l * SZ_M;
            wm2  = wm2A  + (long long)l * SZ_M;
        } else {
            wqkv = wqkvA; wm1 = wm1A; wm2 = wm2A;
            cvt_bf16_k<<<(int)(SZ_QKV / 4 / 256), 256, 0, stream>>>(qkvw + (long long)l * SZ_QKV, wqkv, (int)(SZ_QKV / 4));
            cvt_bf16_k<<<(int)(SZ_M / 4 / 256),   256, 0, stream>>>(m1w  + (long long)l * SZ_M,   wm1,  (int)(SZ_M / 4));
            cvt_bf16_k<<<(int)(SZ_M / 4 / 256),   256, 0, stream>>>(m2w  + (long long)l * SZ_M,   wm2,  (int)(SZ_M / 4));
        }

        cond_ln_k<<<dim3(256, 8), 256, 0, stream>>>(h, s1 + (long long)l * 6144, b1 + (long long)l * 6144, hn);

        gemm_k<M_QKV><<<dim3(64, 18, 1), 256, 49152, stream>>>(
            hn, wqkv, 8192, 2304, 768, 0, 0, 0,
            qkvb + (long long)l * 2304, nullptr, nullptr, q, kbuf, vbuf);

        // Vm = V @ Wm^T  (replaces the post-PV out-proj, by associativity);
        // epilogue writes transposed per batch: vmT[b, dout, s]
        gemm64_k<M_VMT><<<dim3(128, 6, 1), 256, 49152, stream>>>(
            vbuf, wmA + (long long)l * SZ_O, 8192, 768, 768, 0, 0, 0,
            nullptr, vmT, nullptr);

        gemm64_k<M_SCORES><<<dim3(16, 8, 8), 256, 49152, stream>>>(
            q, kbuf, 1024, 1024, 768, 1024LL * 768, 1024LL * 768, 1024LL * 1024,
            nullptr, P, nullptr);

        softmax_k<<<dim3(256, 8), 256, 0, stream>>>(P);

        // h += P @ Vm + bm   (attn output + merged out-proj + residual, fused)
        gemm64_k<M_PVRESID><<<dim3(16, 6, 8), 256, 49152, stream>>>(
            P, vmT, 1024, 768, 1024, 1024LL * 1024, 768LL * 1024, 0,
            bmA + (long long)l * 768, nullptr, h);

        cond_ln_k<<<dim3(256, 8), 256, 0, stream>>>(h, s2 + (long long)l * 6144, b2 + (long long)l * 6144, hn);

        gemm_k<M_GELU><<<dim3(64, 24, 1), 256, 49152, stream>>>(
            hn, wm1, 8192, 3072, 768, 0, 0, 0,
            m1b + (long long)l * 3072, mb, nullptr, nullptr, nullptr, nullptr);

        gemm64_k<M_RESID><<<dim3(128, 6, 1), 256, 49152, stream>>>(
            mb, wm2, 8192, 768, 3072, 0, 0, 0,
            m2b + (long long)l * 768, nullptr, h);
    }

    cond_ln_k<<<dim3(256, 8), 256, 0, stream>>>(h, sf, bfb, hn);
    gemm64_k<M_OUT><<<dim3(128, 8, 1), 256, 49152, stream>>>(
        hn, wout, 8192, 1024, 768, 0, 0, 0,
        outb, nullptr, out);
}